// Round 5
// baseline (177.976 us; speedup 1.0000x reference)
//
#include <hip/hip_runtime.h>
#include <cstdint>

using u16 = unsigned short;
using u32 = uint32_t;

typedef __attribute__((ext_vector_type(8))) short bf16x8;   // 8 bf16 = 4 VGPRs
typedef __attribute__((ext_vector_type(4))) float f32x4;    // MFMA accumulator

__device__ __forceinline__ float bf2f(u16 v) { return __uint_as_float(((u32)v) << 16); }
__device__ __forceinline__ u16 f2bf(float f) {
    u32 u = __float_as_uint(f);
    u += 0x7fffu + ((u >> 16) & 1u);   // RNE
    return (u16)(u >> 16);
}
// Native bf16 conversion (RNE); compiler may fuse pairs into v_cvt_pk_bf16_f32.
__device__ __forceinline__ u16 bf16u(float f) {
#if defined(__BF16_MANT_DIG__)
    __bf16 h = (__bf16)f;
    return __builtin_bit_cast(u16, h);
#else
    return f2bf(f);
#endif
}

// ---- workspace float offsets ----
#define FLAG_OFF 0
#define ZERO_OFF 8         // 16 floats of guaranteed zeros (written by prep)
#define WSH_OFF  2097168   // conv weight bf16 fragments: u16[442368] = 221184 f
#define AWF_OFF  2588688   // 4096
#define CBF_OFF  2592784   // 192
#define QBF_OFF  2592976   // 192
#define ABF_OFF  2593168   // 64
#define KRW_OFF  2593232   // 504
#define KRH_OFF  2593736   // 504
#define KB_OFF   2594240   // kbuf bf16: u16[524288] (uses half the slot)
#define QB_OFF   3118528   // qbuf f32: 524288
#define VB_OFF   3642816   // vbuf bf16: u16[524288]
#define AT_OFF   4167104   // 524288
#define WSHQ_OFF 9409984   // qkv weight bf16 fragments: u16[49152] = 24576 f

// ---------------------------------------------------------------------------
// Dtype sniffer (verified; returns 0 on this problem's fp32 inputs).
// ---------------------------------------------------------------------------
__global__ void detect_kernel(const u16* __restrict__ x, int* __restrict__ flag) {
    __shared__ int cnt;
    if (threadIdx.x == 0) cnt = 0;
    __syncthreads();
    int c = 0;
    #pragma unroll
    for (int k = 0; k < 16; k++) {
        u16 v = x[threadIdx.x * 16 + k];
        int e = (v >> 7) & 0xFF;
        c += (e >= 110 && e <= 140) ? 1 : 0;
    }
    atomicAdd(&cnt, c);
    __syncthreads();
    if (threadIdx.x == 0) *flag = (cnt > 3300) ? 1 : 0;   // 1 = bf16 inputs
}

// ---------------------------------------------------------------------------
// Merged prep: wshufC (blocks 0..215), wshufQ (216..239), small cvt (240..261).
// Bodies identical to the R11-verified kernels.  + zeros the 64B zbuf region.
// ---------------------------------------------------------------------------
__global__ __launch_bounds__(256) void prep_kernel(
    const void* __restrict__ cw, const void* __restrict__ qw,
    const void* __restrict__ cb, const void* __restrict__ qb,
    const void* __restrict__ aw, const void* __restrict__ ab,
    const void* __restrict__ kw_, const void* __restrict__ kh_,
    u16* __restrict__ wshC, u16* __restrict__ wshQ,
    float* __restrict__ cbf, float* __restrict__ qbf, float* __restrict__ awf,
    float* __restrict__ abf, float* __restrict__ krw, float* __restrict__ krh,
    float* __restrict__ zbuf, const int* __restrict__ flag)
{
    const int blk = blockIdx.x;
    const int fl = *flag;
    if (blk < 240) {                         // weight shuffles into B-fragment order
        const void* w; u16* o; int g;
        if (blk < 216) { w = cw; o = wshC; g = blk * 256 + threadIdx.x; }
        else           { w = qw; o = wshQ; g = (blk - 216) * 256 + threadIdx.x; }
        const int kk = g / 768, rem = g % 768;
        const int tile = rem >> 6, lane = rem & 63;
        const int n = tile * 16 + (lane & 15);
        u16 tmp[8];
        #pragma unroll
        for (int j = 0; j < 8; j++) {
            const size_t k = (size_t)(kk * 32 + ((lane >> 4) << 3) + j);
            tmp[j] = fl ? ((const u16*)w)[k * 192 + n]
                        : f2bf(((const float*)w)[k * 192 + n]);
        }
        *(uint4*)(o + (size_t)g * 8) = *(const uint4*)tmp;
    } else {                                 // small-tensor fp32 normalize
        const int gid = (blk - 240) * 256 + threadIdx.x;
        const void* src; float* dst; int e;
        if      (gid <  192) { src = cb;  dst = cbf; e = gid; }
        else if (gid <  384) { src = qb;  dst = qbf; e = gid - 192; }
        else if (gid < 4480) { src = aw;  dst = awf; e = gid - 384; }
        else if (gid < 4544) { src = ab;  dst = abf; e = gid - 4480; }
        else if (gid < 5048) { src = kw_; dst = krw; e = gid - 4544; }
        else if (gid < 5552) { src = kh_; dst = krh; e = gid - 5048; }
        else if (gid < 5568) { zbuf[gid - 5552] = 0.f; return; }
        else return;
        dst[e] = fl ? bf2f(((const u16*)src)[e]) : ((const float*)src)[e];
    }
}

// ---------------------------------------------------------------------------
// QKV implicit GEMM, bf16 MFMA (R10/R11-verified body). Epilogue change:
// k and v are written as bf16 (identical numerics — attn f2bf'd them anyway);
// q stays f32 with scale 8^-0.5 * log2(e).
// ---------------------------------------------------------------------------
__global__ __launch_bounds__(256) void qkv_mfma_kernel(
    const void* __restrict__ xr, const u16* __restrict__ wsh, const float* __restrict__ qbf_,
    const int* __restrict__ flag,
    u16* __restrict__ kb16, float* __restrict__ qbuf, u16* __restrict__ vb16)
{
    const int coh = blockIdx.x, row = blockIdx.y;
    const int b = row >> 5, h = row & 31;
    const int t = threadIdx.x;
    __shared__ u16 xs[32 * 264];                            // 16896 B
    const int fl = *flag;

    if (fl) {
        const u16* src = (const u16*)xr + (size_t)row * 8192;
        #pragma unroll
        for (int i = 0; i < 4; ++i) {
            const int idx = t + i * 256;
            const int px = idx >> 5, cq = idx & 31;
            *(uint4*)(xs + px * 264 + cq * 8) = *(const uint4*)(src + px * 256 + cq * 8);
        }
    } else {
        const float* src = (const float*)xr + (size_t)row * 8192;
        #pragma unroll
        for (int i = 0; i < 8; ++i) {
            const int idx = t + i * 256;
            const int px = idx >> 6, c4 = idx & 63;
            float4 v = *(const float4*)(src + px * 256 + c4 * 4);
            u32 lo = (u32)f2bf(v.x) | ((u32)f2bf(v.y) << 16);
            u32 hi = (u32)f2bf(v.z) | ((u32)f2bf(v.w) << 16);
            *(uint2*)(xs + px * 264 + c4 * 4) = make_uint2(lo, hi);
        }
    }
    __syncthreads();

    const int lane = t & 63, wave = t >> 6;
    const int Mtile = wave & 1;
    const int tg0 = coh * 6 + (wave >> 1) * 3;
    const int l15 = lane & 15, quad = lane >> 4;

    f32x4 acc[3] = {{0,0,0,0},{0,0,0,0},{0,0,0,0}};

    const u16* ap = xs + (Mtile * 16 + l15) * 264 + quad * 8;
    #pragma unroll
    for (int kk = 0; kk < 8; ++kk) {
        const bf16x8 av = *(const bf16x8*)(ap + kk * 32);
        const u16* wp = wsh + ((size_t)(kk * 12 + tg0) * 64 + lane) * 8;
        const bf16x8 b0 = *(const bf16x8*)(wp);
        const bf16x8 b1 = *(const bf16x8*)(wp + 512);
        const bf16x8 b2 = *(const bf16x8*)(wp + 1024);
        acc[0] = __builtin_amdgcn_mfma_f32_16x16x32_bf16(av, b0, acc[0], 0, 0, 0);
        acc[1] = __builtin_amdgcn_mfma_f32_16x16x32_bf16(av, b1, acc[1], 0, 0, 0);
        acc[2] = __builtin_amdgcn_mfma_f32_16x16x32_bf16(av, b2, acc[2], 0, 0, 0);
    }

    // D layout (verified): col = lane&15, row = quad*4 + reg
    const int px0 = Mtile * 16 + quad * 4;
    #pragma unroll
    for (int ti = 0; ti < 3; ++ti) {
        const int tg = tg0 + ti;
        const int o = tg * 16 + l15;
        const int third = tg >> 2;                          // 0=k,1=q,2=v (wave-uniform)
        const int within = o - third * 64;
        const int n = within >> 3, d = within & 7;
        const float bias = qbf_[o];
        #pragma unroll
        for (int r = 0; r < 4; ++r) {
            const int i = h * 32 + px0 + r;
            const size_t off = ((size_t)(b * 8 + n) * 1024 + i) * 8 + d;
            const float val = acc[ti][r] + bias;
            if (third == 0)      kb16[off] = f2bf(val);
            else if (third == 1) qbuf[off] = val * 0.51006973050f;  // 8^-.5 * log2e
            else                 vb16[off] = f2bf(val);
        }
    }
}

// ---------------------------------------------------------------------------
// Conv 3x3 implicit GEMM, bf16 MFMA. VERIFIED — unchanged.
// ---------------------------------------------------------------------------
__global__ __launch_bounds__(256) void conv_mfma_kernel(
    const void* __restrict__ xr, const u16* __restrict__ wsh, const float* __restrict__ cbf,
    const int* __restrict__ flag, void* __restrict__ out)
{
    const int coh = blockIdx.x, row = blockIdx.y;
    const int b = row >> 5, h = row & 31;
    const int t = threadIdx.x;
    __shared__ u16 xs[3 * 34 * 264];                        // 53856 B
    const int fl = *flag;

    #pragma unroll
    for (int r = 0; r < 3; ++r) {
        const int hh = h + r - 1;
        if (t < 64) {
            const int s = (t >> 5) ? 33 : 0, cq = t & 31;
            *(uint4*)(xs + (r * 34 + s) * 264 + cq * 8) = make_uint4(0, 0, 0, 0);
        }
        const bool ok = (hh >= 0) && (hh < 32);
        const size_t base = ((size_t)((b * 32 + (ok ? hh : 0)) * 32)) * 256;
        if (fl) {
            const u16* src = (const u16*)xr + base;
            #pragma unroll
            for (int i = 0; i < 4; ++i) {
                const int idx = t + i * 256;
                const int px = idx >> 5, cq = idx & 31;
                uint4 v = ok ? *(const uint4*)(src + px * 256 + cq * 8)
                             : make_uint4(0, 0, 0, 0);
                *(uint4*)(xs + (r * 34 + 1 + px) * 264 + cq * 8) = v;
            }
        } else {
            const float* src = (const float*)xr + base;
            #pragma unroll
            for (int i = 0; i < 8; ++i) {
                const int idx = t + i * 256;
                const int px = idx >> 6, c4 = idx & 63;
                float4 v = ok ? *(const float4*)(src + px * 256 + c4 * 4)
                              : make_float4(0.f, 0.f, 0.f, 0.f);
                u32 lo = (u32)f2bf(v.x) | ((u32)f2bf(v.y) << 16);
                u32 hi = (u32)f2bf(v.z) | ((u32)f2bf(v.w) << 16);
                *(uint2*)(xs + (r * 34 + 1 + px) * 264 + c4 * 4) = make_uint2(lo, hi);
            }
        }
    }
    __syncthreads();

    const int lane = t & 63, wave = t >> 6;
    const int Mtile = wave & 1;
    const int tg0 = coh * 6 + (wave >> 1) * 3;
    const int l15 = lane & 15, quad = lane >> 4;

    f32x4 acc[3] = {{0,0,0,0},{0,0,0,0},{0,0,0,0}};

    #pragma unroll
    for (int p = 0; p < 9; ++p) {
        const int kh = p / 3, kw = p - kh * 3;
        const u16* ap = xs + (kh * 34 + kw + Mtile * 16 + l15) * 264 + quad * 8;
        #pragma unroll
        for (int ck = 0; ck < 8; ++ck) {
            const int kk = p * 8 + ck;
            const bf16x8 av = *(const bf16x8*)(ap + ck * 32);
            const u16* wp = wsh + ((size_t)(kk * 12 + tg0) * 64 + lane) * 8;
            const bf16x8 b0 = *(const bf16x8*)(wp);
            const bf16x8 b1 = *(const bf16x8*)(wp + 512);
            const bf16x8 b2 = *(const bf16x8*)(wp + 1024);
            acc[0] = __builtin_amdgcn_mfma_f32_16x16x32_bf16(av, b0, acc[0], 0, 0, 0);
            acc[1] = __builtin_amdgcn_mfma_f32_16x16x32_bf16(av, b1, acc[1], 0, 0, 0);
            acc[2] = __builtin_amdgcn_mfma_f32_16x16x32_bf16(av, b2, acc[2], 0, 0, 0);
        }
    }

    const int px0 = Mtile * 16 + quad * 4;
    #pragma unroll
    for (int ti = 0; ti < 3; ++ti) {
        const int co = (tg0 + ti) * 16 + l15;
        const float bias = cbf[co];
        #pragma unroll
        for (int r = 0; r < 4; ++r) {
            const size_t oidx = ((size_t)row * 32 + px0 + r) * 256 + co;
            const float v = acc[ti][r] + bias;
            if (fl) ((u16*)out)[oidx] = f2bf(v);
            else    ((float*)out)[oidx] = v;
        }
    }
}

// ---------------------------------------------------------------------------
// MFMA flash attention v7 — swapped QK^T, SAME-LANE key partition (no
// cross-lane exchange at all; v5/v6's exchange machinery eliminated).
// Derivation from the GEMM-verified fragment layouts
//   A[row=l15][k=quad*8+j], B[k=quad*8+j][col=l15], D[row=quad*4+r][col=l15]:
//   acc0 = mfma(A=K(pi0), B=Q), pi0(m) = 8*(m>>2) + (m&3):
//     lane (l15,quad) reg r = S[c*32 + 8*quad + r][q=l15]       (keys j=0..3)
//   acc1 = mfma(A=K(pi1), B=Q), pi1(m) = 8*(m>>2) + 4 + (m&3):
//     lane (l15,quad) reg r = S[c*32 + 8*quad + 4 + r][q=l15]   (keys j=4..7)
//   => the PV B-fragment (B[k=quad*8+j][col=l15] = P[key][q]) assembles
//      ENTIRELY from the lane's own acc0/acc1 after exp2 — zero lane traffic.
//   RW term: acc += mfma(A=S_sel, B=Arw); Arw register content (rw[q][w] at
//     lane (l15=q, slot=8*quad+j=w)) is rw^T as a B-operand; S_sel puts 1.0
//     at slot pi(row):  S0: quad==l15>>2, elem l15&3;  S1: same quad, elem
//     4+(l15&3).  RH term: per-column scalar C-init (chunk c = h_k).
//   A k>=8 slots are multiplied by B's zero rows (Aq quads 1-3 zeroed), so
//   they are don't-care; zb keeps them zero anyway.
//   PV: oacc = mfma(A = V^T rows 0-7 / ones rows 8-15, B = P-fragment);
//     D2 rows 8-15 accumulate the softmax denominator l[q].
// No inline asm anywhere (m240: compiler fuses native bf16 cast pairs).
// LDS: 16512 + 5120 + 8704 = 30336 B.
// ---------------------------------------------------------------------------
__global__ __launch_bounds__(256) void attn_mfma_kernel(
    const u16* __restrict__ kb16, const float* __restrict__ qbuf, const u16* __restrict__ vb16,
    const float* __restrict__ krw, const float* __restrict__ krh,
    const u16* __restrict__ zb, float* __restrict__ attnbuf)
{
    const int qb = blockIdx.x;           // 0..15 (64 q-rows each)
    const int bn = blockIdx.y;           // 0..63
    const int b = bn >> 3, hn = bn & 7;
    const int t = threadIdx.x;
    const int i0 = qb * 64;

    __shared__ __align__(16) u16   sVT[8 * 1032];   // [d][key] bf16 (pad)  16512 B
    __shared__ __align__(16) u16   sRW[64 * 40];    // [ilocal][wk] bf16     5120 B
    __shared__ __align__(16) float sRH[32 * 68];    // [hk][ilocal] f32      8704 B

    // ---- stage V^T from bf16 vbuf (no conversion) — verified ----
    const u16* vg = vb16 + (size_t)bn * 8192;
    #pragma unroll
    for (int k4 = 0; k4 < 4; k4++) {
        const int key = t + k4 * 256;                 // 0..1023
        uint4 vv = *(const uint4*)(vg + key * 8);
        sVT[0 * 1032 + key] = (u16)(vv.x);  sVT[1 * 1032 + key] = (u16)(vv.x >> 16);
        sVT[2 * 1032 + key] = (u16)(vv.y);  sVT[3 * 1032 + key] = (u16)(vv.y >> 16);
        sVT[4 * 1032 + key] = (u16)(vv.z);  sVT[5 * 1032 + key] = (u16)(vv.z >> 16);
        sVT[6 * 1032 + key] = (u16)(vv.w);  sVT[7 * 1032 + key] = (u16)(vv.w >> 16);
    }
    // ---- rel tables: rw (bf16) and rh (f32 C-init) — verified ----
    #pragma unroll
    for (int k8 = 0; k8 < 8; k8++) {
        const int idx = t + k8 * 256;                 // 0..2047
        const int il = idx >> 5, w = idx & 31;
        const int i = i0 + il;
        const float* q = qbuf + ((size_t)bn * 1024 + i) * 8;
        float4 qa = *(const float4*)q, qc = *(const float4*)(q + 4);
        const float* rp = krw + (size_t)(w - (i & 31) + 31) * 8;
        float4 ra = *(const float4*)rp, rc = *(const float4*)(rp + 4);
        sRW[il * 40 + w] = f2bf(qa.x*ra.x + qa.y*ra.y + qa.z*ra.z + qa.w*ra.w
                              + qc.x*rc.x + qc.y*rc.y + qc.z*rc.z + qc.w*rc.w);
        const float* hp = krh + (size_t)(w - (i >> 5) + 31) * 8;
        float4 ha = *(const float4*)hp, hc = *(const float4*)(hp + 4);
        sRH[w * 68 + il] = qa.x*ha.x + qa.y*ha.y + qa.z*ha.z + qa.w*ha.w
                         + qc.x*hc.x + qc.y*hc.y + qc.z*hc.z + qc.w*hc.w;
    }
    __syncthreads();

    const int lane = t & 63, wave = t >> 6;
    const int l15 = lane & 15, quad = lane >> 4;

    union Frag { u16 a[8]; bf16x8 v; };
    Frag Aq;                                   // Q fragment (B operand), verified load
    {
        const float* q = qbuf + ((size_t)bn * 1024 + i0 + wave * 16 + l15) * 8;
        float4 qa = *(const float4*)q, qc = *(const float4*)(q + 4);
        Aq.a[0] = f2bf(qa.x); Aq.a[1] = f2bf(qa.y); Aq.a[2] = f2bf(qa.z); Aq.a[3] = f2bf(qa.w);
        Aq.a[4] = f2bf(qc.x); Aq.a[5] = f2bf(qc.y); Aq.a[6] = f2bf(qc.z); Aq.a[7] = f2bf(qc.w);
        if (quad != 0) {
            #pragma unroll
            for (int j = 0; j < 8; j++) Aq.a[j] = 0;
        }
    }
    // RW fragment: same register content as the verified kernel; used as B.
    const bf16x8 Arw = *(const bf16x8*)(sRW + (wave * 16 + l15) * 40 + quad * 8);

    // Selector fragments (A-operands of the RW mfma):
    //   S0[row=l15][k] = 1 iff k == pi0(l15) = 8*(l15>>2) + (l15&3)
    //   S1[row=l15][k] = 1 iff k == pi1(l15) = 8*(l15>>2) + 4 + (l15&3)
    Frag S0, S1, ONE;
    #pragma unroll
    for (int j = 0; j < 8; j++) { S0.a[j] = 0; S1.a[j] = 0; ONE.a[j] = 0x3F80; }
    if (quad == (l15 >> 2)) {
        S0.a[l15 & 3]       = 0x3F80;
        S1.a[4 + (l15 & 3)] = 0x3F80;
    }

    // K row pointers: quad 0 reads permuted K rows; quads 1-3 read zeros
    // (don't-care slots — Aq's k>=8 rows are zero — kept zero for safety).
    const u16* kg = kb16 + (size_t)bn * 8192;
    const u16* kp0; const u16* kp1; int kst;
    if (quad == 0) {
        const int s = l15 >> 2, r = l15 & 3;
        kp0 = kg + (size_t)(8 * s + r) * 8;                      // pi0
        kp1 = kg + (size_t)(8 * s + 4 + r) * 8;                  // pi1 = pi0 + 4 rows
        kst = 256;                                               // 32 keys * 8 u16
    } else { kp0 = zb; kp1 = zb; kst = 0; }

    f32x4 oacc = {0.f, 0.f, 0.f, 0.f};

    bf16x8 kA = *(const bf16x8*)kp0;
    bf16x8 kB = *(const bf16x8*)kp1;

    for (int c = 0; c < 32; ++c) {
        bf16x8 kA2 = kA, kB2 = kB;
        if (c + 1 < 32) {                      // prefetch next chunk's K rows
            kA2 = *(const bf16x8*)(kp0 + kst);
            kB2 = *(const bf16x8*)(kp1 + kst);
            kp0 += kst; kp1 += kst;
        }
        const float rhv = sRH[c * 68 + wave * 16 + l15];   // per-column C-init
        f32x4 acc0 = {rhv, rhv, rhv, rhv};
        f32x4 acc1 = acc0;
        acc0 = __builtin_amdgcn_mfma_f32_16x16x32_bf16(kA,   Aq.v, acc0, 0, 0, 0);
        acc0 = __builtin_amdgcn_mfma_f32_16x16x32_bf16(S0.v, Arw,  acc0, 0, 0, 0);
        acc1 = __builtin_amdgcn_mfma_f32_16x16x32_bf16(kB,   Aq.v, acc1, 0, 0, 0);
        acc1 = __builtin_amdgcn_mfma_f32_16x16x32_bf16(S1.v, Arw,  acc1, 0, 0, 0);
        kA = kA2; kB = kB2;

        // exp2 (inputs pre-scaled by log2e):
        //   acc0[r] = S[c*32 + 8*quad + r][q=l15]       -> PV slots j = r
        //   acc1[r] = S[c*32 + 8*quad + 4 + r][q=l15]   -> PV slots j = 4+r
        union { u16 a[8]; bf16x8 v; } pf;
        pf.a[0] = bf16u(exp2f(fminf(acc0[0], 80.0f)));
        pf.a[1] = bf16u(exp2f(fminf(acc0[1], 80.0f)));
        pf.a[2] = bf16u(exp2f(fminf(acc0[2], 80.0f)));
        pf.a[3] = bf16u(exp2f(fminf(acc0[3], 80.0f)));
        pf.a[4] = bf16u(exp2f(fminf(acc1[0], 80.0f)));
        pf.a[5] = bf16u(exp2f(fminf(acc1[1], 80.0f)));
        pf.a[6] = bf16u(exp2f(fminf(acc1[2], 80.0f)));
        pf.a[7] = bf16u(exp2f(fminf(acc1[3], 80.0f)));

        bf16x8 Av;                           // V/ones fragment (A operand)
        if (l15 < 8) Av = *(const bf16x8*)(sVT + l15 * 1032 + c * 32 + quad * 8);
        else         Av = ONE.v;             // rows 8-15 -> denominator l
        oacc = __builtin_amdgcn_mfma_f32_16x16x32_bf16(Av, pf.v, oacc, 0, 0, 0);
    }

    // D2[row][q=l15]: rows 0-7 = O^T[d][q] (quads 0,1), rows 8-15 = l[q].
    const float lr = __shfl(oacc[0], 32 + l15, 64);       // (l15, quad=2) row 8
    const float inv = 1.0f / fmaxf(lr, 1e-30f);
    if (quad < 2) {
        float4 o;
        o.x = oacc[0] * inv; o.y = oacc[1] * inv;
        o.z = oacc[2] * inv; o.w = oacc[3] * inv;
        *(float4*)(attnbuf + ((size_t)b * 1024 + i0 + wave * 16 + l15) * 64
                   + hn * 8 + quad * 4) = o;
    }
}

// ---------------------------------------------------------------------------
// Output projection (VERIFIED — unchanged).
// ---------------------------------------------------------------------------
__global__ __launch_bounds__(256) void proj_kernel(
    const float* __restrict__ attnbuf, const float* __restrict__ awf, const float* __restrict__ abf,
    const int* __restrict__ flag, void* __restrict__ out)
{
    const int g = blockIdx.x * 256 + threadIdx.x;
    const int px = g >> 6, o = g & 63;
    const float* ar = attnbuf + (size_t)px * 64;
    float acc = abf[o];
    #pragma unroll 8
    for (int c = 0; c < 64; c++) acc += ar[c] * awf[c * 64 + o];
    if (*flag) ((u16*)out)[(size_t)px * 256 + 192 + o] = f2bf(acc);
    else       ((float*)out)[(size_t)px * 256 + 192 + o] = acc;
}

// ---------------------------------------------------------------------------
extern "C" void kernel_launch(void* const* d_in, const int* in_sizes, int n_in,
                              void* d_out, int out_size, void* d_ws, size_t ws_size,
                              hipStream_t stream)
{
    float* ws = (float*)d_ws;
    int*   flag = (int*)(ws + FLAG_OFF);
    float* zbuf = ws + ZERO_OFF;
    u16*   wsh  = (u16*)(ws + WSH_OFF);
    float* awf  = ws + AWF_OFF;
    float* cbf  = ws + CBF_OFF;
    float* qbf  = ws + QBF_OFF;
    float* abf  = ws + ABF_OFF;
    float* krw  = ws + KRW_OFF;
    float* krh  = ws + KRH_OFF;
    u16*   kb16 = (u16*)(ws + KB_OFF);
    float* qbuf = ws + QB_OFF;
    u16*   vb16 = (u16*)(ws + VB_OFF);
    float* atb  = ws + AT_OFF;
    u16*   wshQ = (u16*)(ws + WSHQ_OFF);

    detect_kernel<<<1, 256, 0, stream>>>((const u16*)d_in[0], flag);

    prep_kernel<<<262, 256, 0, stream>>>(
        d_in[1], d_in[3], d_in[2], d_in[4], d_in[5], d_in[6], d_in[7], d_in[8],
        wsh, wshQ, cbf, qbf, awf, abf, krw, krh, zbuf, flag);

    qkv_mfma_kernel <<<dim3(2, 256), 256, 0, stream>>>(d_in[0], wshQ, qbf, flag, kb16, qbuf, vb16);
    conv_mfma_kernel<<<dim3(2, 256), 256, 0, stream>>>(d_in[0], wsh, cbf, flag, d_out);
    attn_mfma_kernel<<<dim3(16, 64), 256, 0, stream>>>(kb16, qbuf, vb16, krw, krh,
                                                       (const u16*)zbuf, atb);
    proj_kernel     <<<2048,         256, 0, stream>>>(atb, awf, abf, flag, d_out);
}

// Round 6
// 170.759 us; speedup vs baseline: 1.0423x; 1.0423x over previous
//
#include <hip/hip_runtime.h>
#include <cstdint>

using u16 = unsigned short;
using u32 = uint32_t;

typedef __attribute__((ext_vector_type(8))) short bf16x8;   // 8 bf16 = 4 VGPRs
typedef __attribute__((ext_vector_type(4))) float f32x4;    // MFMA accumulator

__device__ __forceinline__ float bf2f(u16 v) { return __uint_as_float(((u32)v) << 16); }
__device__ __forceinline__ u16 f2bf(float f) {
    u32 u = __float_as_uint(f);
    u += 0x7fffu + ((u >> 16) & 1u);   // RNE
    return (u16)(u >> 16);
}
// Native bf16 conversion (RNE); compiler may fuse pairs into v_cvt_pk_bf16_f32.
__device__ __forceinline__ u16 bf16u(float f) {
#if defined(__BF16_MANT_DIG__)
    __bf16 h = (__bf16)f;
    return __builtin_bit_cast(u16, h);
#else
    return f2bf(f);
#endif
}

// ---- workspace float offsets ----
#define FLAG_OFF 0
#define ZERO_OFF 8         // 16 floats of guaranteed zeros (written by prep)
#define WSH_OFF  2097168   // conv weight bf16 fragments: u16[442368] = 221184 f
#define AWF_OFF  2588688   // 4096
#define CBF_OFF  2592784   // 192
#define QBF_OFF  2592976   // 192
#define ABF_OFF  2593168   // 64
#define KRW_OFF  2593232   // 504
#define KRH_OFF  2593736   // 504
#define KB_OFF   2594240   // kbuf bf16: u16[524288] (uses half the slot)
#define QB_OFF   3118528   // qbuf f32: 524288
#define VB_OFF   3642816   // vbuf bf16: u16[524288]
#define AT_OFF   4167104   // 524288
#define WSHQ_OFF 9409984   // qkv weight bf16 fragments: u16[49152] = 24576 f

// ---------------------------------------------------------------------------
// Dtype sniffer (verified; returns 0 on this problem's fp32 inputs).
// ---------------------------------------------------------------------------
__global__ void detect_kernel(const u16* __restrict__ x, int* __restrict__ flag) {
    __shared__ int cnt;
    if (threadIdx.x == 0) cnt = 0;
    __syncthreads();
    int c = 0;
    #pragma unroll
    for (int k = 0; k < 16; k++) {
        u16 v = x[threadIdx.x * 16 + k];
        int e = (v >> 7) & 0xFF;
        c += (e >= 110 && e <= 140) ? 1 : 0;
    }
    atomicAdd(&cnt, c);
    __syncthreads();
    if (threadIdx.x == 0) *flag = (cnt > 3300) ? 1 : 0;   // 1 = bf16 inputs
}

// ---------------------------------------------------------------------------
// Merged prep: wshufC (blocks 0..215), wshufQ (216..239), small cvt (240..261).
// Bodies identical to the R11-verified kernels.  + zeros the 64B zbuf region.
// ---------------------------------------------------------------------------
__global__ __launch_bounds__(256) void prep_kernel(
    const void* __restrict__ cw, const void* __restrict__ qw,
    const void* __restrict__ cb, const void* __restrict__ qb,
    const void* __restrict__ aw, const void* __restrict__ ab,
    const void* __restrict__ kw_, const void* __restrict__ kh_,
    u16* __restrict__ wshC, u16* __restrict__ wshQ,
    float* __restrict__ cbf, float* __restrict__ qbf, float* __restrict__ awf,
    float* __restrict__ abf, float* __restrict__ krw, float* __restrict__ krh,
    float* __restrict__ zbuf, const int* __restrict__ flag)
{
    const int blk = blockIdx.x;
    const int fl = *flag;
    if (blk < 240) {                         // weight shuffles into B-fragment order
        const void* w; u16* o; int g;
        if (blk < 216) { w = cw; o = wshC; g = blk * 256 + threadIdx.x; }
        else           { w = qw; o = wshQ; g = (blk - 216) * 256 + threadIdx.x; }
        const int kk = g / 768, rem = g % 768;
        const int tile = rem >> 6, lane = rem & 63;
        const int n = tile * 16 + (lane & 15);
        u16 tmp[8];
        #pragma unroll
        for (int j = 0; j < 8; j++) {
            const size_t k = (size_t)(kk * 32 + ((lane >> 4) << 3) + j);
            tmp[j] = fl ? ((const u16*)w)[k * 192 + n]
                        : f2bf(((const float*)w)[k * 192 + n]);
        }
        *(uint4*)(o + (size_t)g * 8) = *(const uint4*)tmp;
    } else {                                 // small-tensor fp32 normalize
        const int gid = (blk - 240) * 256 + threadIdx.x;
        const void* src; float* dst; int e;
        if      (gid <  192) { src = cb;  dst = cbf; e = gid; }
        else if (gid <  384) { src = qb;  dst = qbf; e = gid - 192; }
        else if (gid < 4480) { src = aw;  dst = awf; e = gid - 384; }
        else if (gid < 4544) { src = ab;  dst = abf; e = gid - 4480; }
        else if (gid < 5048) { src = kw_; dst = krw; e = gid - 4544; }
        else if (gid < 5552) { src = kh_; dst = krh; e = gid - 5048; }
        else if (gid < 5568) { zbuf[gid - 5552] = 0.f; return; }
        else return;
        dst[e] = fl ? bf2f(((const u16*)src)[e]) : ((const float*)src)[e];
    }
}

// ---------------------------------------------------------------------------
// QKV implicit GEMM, bf16 MFMA (R10/R11-verified body). Epilogue change:
// k and v are written as bf16 (identical numerics — attn f2bf'd them anyway);
// q stays f32 with scale 8^-0.5 * log2(e).
// ---------------------------------------------------------------------------
__global__ __launch_bounds__(256) void qkv_mfma_kernel(
    const void* __restrict__ xr, const u16* __restrict__ wsh, const float* __restrict__ qbf_,
    const int* __restrict__ flag,
    u16* __restrict__ kb16, float* __restrict__ qbuf, u16* __restrict__ vb16)
{
    const int coh = blockIdx.x, row = blockIdx.y;
    const int b = row >> 5, h = row & 31;
    const int t = threadIdx.x;
    __shared__ u16 xs[32 * 264];                            // 16896 B
    const int fl = *flag;

    if (fl) {
        const u16* src = (const u16*)xr + (size_t)row * 8192;
        #pragma unroll
        for (int i = 0; i < 4; ++i) {
            const int idx = t + i * 256;
            const int px = idx >> 5, cq = idx & 31;
            *(uint4*)(xs + px * 264 + cq * 8) = *(const uint4*)(src + px * 256 + cq * 8);
        }
    } else {
        const float* src = (const float*)xr + (size_t)row * 8192;
        #pragma unroll
        for (int i = 0; i < 8; ++i) {
            const int idx = t + i * 256;
            const int px = idx >> 6, c4 = idx & 63;
            float4 v = *(const float4*)(src + px * 256 + c4 * 4);
            u32 lo = (u32)f2bf(v.x) | ((u32)f2bf(v.y) << 16);
            u32 hi = (u32)f2bf(v.z) | ((u32)f2bf(v.w) << 16);
            *(uint2*)(xs + px * 264 + c4 * 4) = make_uint2(lo, hi);
        }
    }
    __syncthreads();

    const int lane = t & 63, wave = t >> 6;
    const int Mtile = wave & 1;
    const int tg0 = coh * 6 + (wave >> 1) * 3;
    const int l15 = lane & 15, quad = lane >> 4;

    f32x4 acc[3] = {{0,0,0,0},{0,0,0,0},{0,0,0,0}};

    const u16* ap = xs + (Mtile * 16 + l15) * 264 + quad * 8;
    #pragma unroll
    for (int kk = 0; kk < 8; ++kk) {
        const bf16x8 av = *(const bf16x8*)(ap + kk * 32);
        const u16* wp = wsh + ((size_t)(kk * 12 + tg0) * 64 + lane) * 8;
        const bf16x8 b0 = *(const bf16x8*)(wp);
        const bf16x8 b1 = *(const bf16x8*)(wp + 512);
        const bf16x8 b2 = *(const bf16x8*)(wp + 1024);
        acc[0] = __builtin_amdgcn_mfma_f32_16x16x32_bf16(av, b0, acc[0], 0, 0, 0);
        acc[1] = __builtin_amdgcn_mfma_f32_16x16x32_bf16(av, b1, acc[1], 0, 0, 0);
        acc[2] = __builtin_amdgcn_mfma_f32_16x16x32_bf16(av, b2, acc[2], 0, 0, 0);
    }

    // D layout (verified): col = lane&15, row = quad*4 + reg
    const int px0 = Mtile * 16 + quad * 4;
    #pragma unroll
    for (int ti = 0; ti < 3; ++ti) {
        const int tg = tg0 + ti;
        const int o = tg * 16 + l15;
        const int third = tg >> 2;                          // 0=k,1=q,2=v (wave-uniform)
        const int within = o - third * 64;
        const int n = within >> 3, d = within & 7;
        const float bias = qbf_[o];
        #pragma unroll
        for (int r = 0; r < 4; ++r) {
            const int i = h * 32 + px0 + r;
            const size_t off = ((size_t)(b * 8 + n) * 1024 + i) * 8 + d;
            const float val = acc[ti][r] + bias;
            if (third == 0)      kb16[off] = f2bf(val);
            else if (third == 1) qbuf[off] = val * 0.51006973050f;  // 8^-.5 * log2e
            else                 vb16[off] = f2bf(val);
        }
    }
}

// ---------------------------------------------------------------------------
// Conv 3x3 implicit GEMM, bf16 MFMA. VERIFIED — unchanged.
// ---------------------------------------------------------------------------
__global__ __launch_bounds__(256) void conv_mfma_kernel(
    const void* __restrict__ xr, const u16* __restrict__ wsh, const float* __restrict__ cbf,
    const int* __restrict__ flag, void* __restrict__ out)
{
    const int coh = blockIdx.x, row = blockIdx.y;
    const int b = row >> 5, h = row & 31;
    const int t = threadIdx.x;
    __shared__ u16 xs[3 * 34 * 264];                        // 53856 B
    const int fl = *flag;

    #pragma unroll
    for (int r = 0; r < 3; ++r) {
        const int hh = h + r - 1;
        if (t < 64) {
            const int s = (t >> 5) ? 33 : 0, cq = t & 31;
            *(uint4*)(xs + (r * 34 + s) * 264 + cq * 8) = make_uint4(0, 0, 0, 0);
        }
        const bool ok = (hh >= 0) && (hh < 32);
        const size_t base = ((size_t)((b * 32 + (ok ? hh : 0)) * 32)) * 256;
        if (fl) {
            const u16* src = (const u16*)xr + base;
            #pragma unroll
            for (int i = 0; i < 4; ++i) {
                const int idx = t + i * 256;
                const int px = idx >> 5, cq = idx & 31;
                uint4 v = ok ? *(const uint4*)(src + px * 256 + cq * 8)
                             : make_uint4(0, 0, 0, 0);
                *(uint4*)(xs + (r * 34 + 1 + px) * 264 + cq * 8) = v;
            }
        } else {
            const float* src = (const float*)xr + base;
            #pragma unroll
            for (int i = 0; i < 8; ++i) {
                const int idx = t + i * 256;
                const int px = idx >> 6, c4 = idx & 63;
                float4 v = ok ? *(const float4*)(src + px * 256 + c4 * 4)
                              : make_float4(0.f, 0.f, 0.f, 0.f);
                u32 lo = (u32)f2bf(v.x) | ((u32)f2bf(v.y) << 16);
                u32 hi = (u32)f2bf(v.z) | ((u32)f2bf(v.w) << 16);
                *(uint2*)(xs + (r * 34 + 1 + px) * 264 + c4 * 4) = make_uint2(lo, hi);
            }
        }
    }
    __syncthreads();

    const int lane = t & 63, wave = t >> 6;
    const int Mtile = wave & 1;
    const int tg0 = coh * 6 + (wave >> 1) * 3;
    const int l15 = lane & 15, quad = lane >> 4;

    f32x4 acc[3] = {{0,0,0,0},{0,0,0,0},{0,0,0,0}};

    #pragma unroll
    for (int p = 0; p < 9; ++p) {
        const int kh = p / 3, kw = p - kh * 3;
        const u16* ap = xs + (kh * 34 + kw + Mtile * 16 + l15) * 264 + quad * 8;
        #pragma unroll
        for (int ck = 0; ck < 8; ++ck) {
            const int kk = p * 8 + ck;
            const bf16x8 av = *(const bf16x8*)(ap + ck * 32);
            const u16* wp = wsh + ((size_t)(kk * 12 + tg0) * 64 + lane) * 8;
            const bf16x8 b0 = *(const bf16x8*)(wp);
            const bf16x8 b1 = *(const bf16x8*)(wp + 512);
            const bf16x8 b2 = *(const bf16x8*)(wp + 1024);
            acc[0] = __builtin_amdgcn_mfma_f32_16x16x32_bf16(av, b0, acc[0], 0, 0, 0);
            acc[1] = __builtin_amdgcn_mfma_f32_16x16x32_bf16(av, b1, acc[1], 0, 0, 0);
            acc[2] = __builtin_amdgcn_mfma_f32_16x16x32_bf16(av, b2, acc[2], 0, 0, 0);
        }
    }

    const int px0 = Mtile * 16 + quad * 4;
    #pragma unroll
    for (int ti = 0; ti < 3; ++ti) {
        const int co = (tg0 + ti) * 16 + l15;
        const float bias = cbf[co];
        #pragma unroll
        for (int r = 0; r < 4; ++r) {
            const size_t oidx = ((size_t)row * 32 + px0 + r) * 256 + co;
            const float v = acc[ti][r] + bias;
            if (fl) ((u16*)out)[oidx] = f2bf(v);
            else    ((float*)out)[oidx] = v;
        }
    }
}

// ---------------------------------------------------------------------------
// MFMA flash attention v8 — v7's verified swapped structure with:
//  - rel-W MFMAs HOISTED (chunk-invariant: wk = key&31 = 8*quad+r does not
//    depend on c): rw0/rw1 computed once, folded into the per-chunk C-init.
//    Per-chunk MFMA count 5 -> 3; dep chain loses one MFMA latency.
//  - PV accumulator split even/odd (oaccE/oaccO) to break the serial
//    cross-chunk PV dependency; summed before the epilogue.
//  - Uniform K addressing for all quads (quads 1-3 rows multiply Q's zero
//    k-rows -> don't-care), restoring broadcast loads; prefetch distance 2.
// LDS: 16512 + 5120 + 8704 = 30336 B.
// ---------------------------------------------------------------------------
#define ATTN_STEP8(C, KA, KB, OACC)                                            \
  do {                                                                         \
    const int c_ = (C);                                                        \
    const float rhv = sRH[c_ * 68 + wave * 16 + l15];                          \
    f32x4 acc0, acc1;                                                          \
    acc0[0] = rhv + rw0[0]; acc0[1] = rhv + rw0[1];                            \
    acc0[2] = rhv + rw0[2]; acc0[3] = rhv + rw0[3];                            \
    acc1[0] = rhv + rw1[0]; acc1[1] = rhv + rw1[1];                            \
    acc1[2] = rhv + rw1[2]; acc1[3] = rhv + rw1[3];                            \
    acc0 = __builtin_amdgcn_mfma_f32_16x16x32_bf16(KA, Aq.v, acc0, 0, 0, 0);   \
    acc1 = __builtin_amdgcn_mfma_f32_16x16x32_bf16(KB, Aq.v, acc1, 0, 0, 0);   \
    if (c_ + 2 < 32) {            /* prefetch 2 chunks ahead (ping-pong) */    \
      KA = *(const bf16x8*)(kp0 + (c_ + 2) * 256);                             \
      KB = *(const bf16x8*)(kp1 + (c_ + 2) * 256);                             \
    }                                                                          \
    union { u16 a[8]; bf16x8 v; } pf;                                          \
    pf.a[0] = bf16u(exp2f(fminf(acc0[0], 80.0f)));                             \
    pf.a[1] = bf16u(exp2f(fminf(acc0[1], 80.0f)));                             \
    pf.a[2] = bf16u(exp2f(fminf(acc0[2], 80.0f)));                             \
    pf.a[3] = bf16u(exp2f(fminf(acc0[3], 80.0f)));                             \
    pf.a[4] = bf16u(exp2f(fminf(acc1[0], 80.0f)));                             \
    pf.a[5] = bf16u(exp2f(fminf(acc1[1], 80.0f)));                             \
    pf.a[6] = bf16u(exp2f(fminf(acc1[2], 80.0f)));                             \
    pf.a[7] = bf16u(exp2f(fminf(acc1[3], 80.0f)));                             \
    bf16x8 Av;                                                                 \
    if (l15 < 8) Av = *(const bf16x8*)(sVT + l15 * 1032 + c_ * 32 + quad * 8); \
    else         Av = ONE.v;                                                   \
    OACC = __builtin_amdgcn_mfma_f32_16x16x32_bf16(Av, pf.v, OACC, 0, 0, 0);   \
  } while (0)

__global__ __launch_bounds__(256) void attn_mfma_kernel(
    const u16* __restrict__ kb16, const float* __restrict__ qbuf, const u16* __restrict__ vb16,
    const float* __restrict__ krw, const float* __restrict__ krh,
    float* __restrict__ attnbuf)
{
    const int qb = blockIdx.x;           // 0..15 (64 q-rows each)
    const int bn = blockIdx.y;           // 0..63
    const int b = bn >> 3, hn = bn & 7;
    const int t = threadIdx.x;
    const int i0 = qb * 64;

    __shared__ __align__(16) u16   sVT[8 * 1032];   // [d][key] bf16 (pad)  16512 B
    __shared__ __align__(16) u16   sRW[64 * 40];    // [ilocal][wk] bf16     5120 B
    __shared__ __align__(16) float sRH[32 * 68];    // [hk][ilocal] f32      8704 B

    // ---- stage V^T from bf16 vbuf (no conversion) — verified ----
    const u16* vg = vb16 + (size_t)bn * 8192;
    #pragma unroll
    for (int k4 = 0; k4 < 4; k4++) {
        const int key = t + k4 * 256;                 // 0..1023
        uint4 vv = *(const uint4*)(vg + key * 8);
        sVT[0 * 1032 + key] = (u16)(vv.x);  sVT[1 * 1032 + key] = (u16)(vv.x >> 16);
        sVT[2 * 1032 + key] = (u16)(vv.y);  sVT[3 * 1032 + key] = (u16)(vv.y >> 16);
        sVT[4 * 1032 + key] = (u16)(vv.z);  sVT[5 * 1032 + key] = (u16)(vv.z >> 16);
        sVT[6 * 1032 + key] = (u16)(vv.w);  sVT[7 * 1032 + key] = (u16)(vv.w >> 16);
    }
    // ---- rel tables: rw (bf16) and rh (f32 C-init) — verified ----
    #pragma unroll
    for (int k8 = 0; k8 < 8; k8++) {
        const int idx = t + k8 * 256;                 // 0..2047
        const int il = idx >> 5, w = idx & 31;
        const int i = i0 + il;
        const float* q = qbuf + ((size_t)bn * 1024 + i) * 8;
        float4 qa = *(const float4*)q, qc = *(const float4*)(q + 4);
        const float* rp = krw + (size_t)(w - (i & 31) + 31) * 8;
        float4 ra = *(const float4*)rp, rc = *(const float4*)(rp + 4);
        sRW[il * 40 + w] = f2bf(qa.x*ra.x + qa.y*ra.y + qa.z*ra.z + qa.w*ra.w
                              + qc.x*rc.x + qc.y*rc.y + qc.z*rc.z + qc.w*rc.w);
        const float* hp = krh + (size_t)(w - (i >> 5) + 31) * 8;
        float4 ha = *(const float4*)hp, hc = *(const float4*)(hp + 4);
        sRH[w * 68 + il] = qa.x*ha.x + qa.y*ha.y + qa.z*ha.z + qa.w*ha.w
                         + qc.x*hc.x + qc.y*hc.y + qc.z*hc.z + qc.w*hc.w;
    }
    __syncthreads();

    const int lane = t & 63, wave = t >> 6;
    const int l15 = lane & 15, quad = lane >> 4;

    union Frag { u16 a[8]; bf16x8 v; };
    Frag Aq;                                   // Q fragment (B operand), verified load
    {
        const float* q = qbuf + ((size_t)bn * 1024 + i0 + wave * 16 + l15) * 8;
        float4 qa = *(const float4*)q, qc = *(const float4*)(q + 4);
        Aq.a[0] = f2bf(qa.x); Aq.a[1] = f2bf(qa.y); Aq.a[2] = f2bf(qa.z); Aq.a[3] = f2bf(qa.w);
        Aq.a[4] = f2bf(qc.x); Aq.a[5] = f2bf(qc.y); Aq.a[6] = f2bf(qc.z); Aq.a[7] = f2bf(qc.w);
        if (quad != 0) {
            #pragma unroll
            for (int j = 0; j < 8; j++) Aq.a[j] = 0;
        }
    }
    // RW fragment: same register content as the verified kernel; used as B.
    const bf16x8 Arw = *(const bf16x8*)(sRW + (wave * 16 + l15) * 40 + quad * 8);

    // Selector fragments (verified in v7): S0 -> k=pi0(l15), S1 -> k=pi1(l15).
    Frag S0, S1, ONE;
    #pragma unroll
    for (int j = 0; j < 8; j++) { S0.a[j] = 0; S1.a[j] = 0; ONE.a[j] = 0x3F80; }
    if (quad == (l15 >> 2)) {
        S0.a[l15 & 3]       = 0x3F80;
        S1.a[4 + (l15 & 3)] = 0x3F80;
    }

    // Hoisted rel-W results (chunk-invariant):
    //   rw0[r] = rw[q=l15][wk = 8*quad + r],  rw1[r] = rw[q=l15][8*quad+4+r]
    f32x4 zero4 = {0.f, 0.f, 0.f, 0.f};
    const f32x4 rw0 = __builtin_amdgcn_mfma_f32_16x16x32_bf16(S0.v, Arw, zero4, 0, 0, 0);
    const f32x4 rw1 = __builtin_amdgcn_mfma_f32_16x16x32_bf16(S1.v, Arw, zero4, 0, 0, 0);

    // K row pointers — uniform across quads (quads 1-3 rows are don't-care:
    // they multiply Aq's zero k-rows). 16 distinct rows per load -> broadcast.
    const u16* kg = kb16 + (size_t)bn * 8192;
    const int s = l15 >> 2, rr = l15 & 3;
    const u16* kp0 = kg + (size_t)(8 * s + rr) * 8;          // pi0 rows
    const u16* kp1 = kg + (size_t)(8 * s + 4 + rr) * 8;      // pi1 rows

    f32x4 oaccE = {0.f, 0.f, 0.f, 0.f};
    f32x4 oaccO = {0.f, 0.f, 0.f, 0.f};

    bf16x8 kAa = *(const bf16x8*)(kp0);
    bf16x8 kBa = *(const bf16x8*)(kp1);
    bf16x8 kAb = *(const bf16x8*)(kp0 + 256);
    bf16x8 kBb = *(const bf16x8*)(kp1 + 256);

    for (int c2 = 0; c2 < 32; c2 += 2) {
        ATTN_STEP8(c2,     kAa, kBa, oaccE);
        ATTN_STEP8(c2 + 1, kAb, kBb, oaccO);
    }

    f32x4 oacc;
    oacc[0] = oaccE[0] + oaccO[0];
    oacc[1] = oaccE[1] + oaccO[1];
    oacc[2] = oaccE[2] + oaccO[2];
    oacc[3] = oaccE[3] + oaccO[3];

    // D2[row][q=l15]: rows 0-7 = O^T[d][q] (quads 0,1), rows 8-15 = l[q].
    const float lr = __shfl(oacc[0], 32 + l15, 64);       // (l15, quad=2) row 8
    const float inv = 1.0f / fmaxf(lr, 1e-30f);
    if (quad < 2) {
        float4 o;
        o.x = oacc[0] * inv; o.y = oacc[1] * inv;
        o.z = oacc[2] * inv; o.w = oacc[3] * inv;
        *(float4*)(attnbuf + ((size_t)b * 1024 + i0 + wave * 16 + l15) * 64
                   + hn * 8 + quad * 4) = o;
    }
}

// ---------------------------------------------------------------------------
// Output projection (VERIFIED — unchanged).
// ---------------------------------------------------------------------------
__global__ __launch_bounds__(256) void proj_kernel(
    const float* __restrict__ attnbuf, const float* __restrict__ awf, const float* __restrict__ abf,
    const int* __restrict__ flag, void* __restrict__ out)
{
    const int g = blockIdx.x * 256 + threadIdx.x;
    const int px = g >> 6, o = g & 63;
    const float* ar = attnbuf + (size_t)px * 64;
    float acc = abf[o];
    #pragma unroll 8
    for (int c = 0; c < 64; c++) acc += ar[c] * awf[c * 64 + o];
    if (*flag) ((u16*)out)[(size_t)px * 256 + 192 + o] = f2bf(acc);
    else       ((float*)out)[(size_t)px * 256 + 192 + o] = acc;
}

// ---------------------------------------------------------------------------
extern "C" void kernel_launch(void* const* d_in, const int* in_sizes, int n_in,
                              void* d_out, int out_size, void* d_ws, size_t ws_size,
                              hipStream_t stream)
{
    float* ws = (float*)d_ws;
    int*   flag = (int*)(ws + FLAG_OFF);
    float* zbuf = ws + ZERO_OFF;
    u16*   wsh  = (u16*)(ws + WSH_OFF);
    float* awf  = ws + AWF_OFF;
    float* cbf  = ws + CBF_OFF;
    float* qbf  = ws + QBF_OFF;
    float* abf  = ws + ABF_OFF;
    float* krw  = ws + KRW_OFF;
    float* krh  = ws + KRH_OFF;
    u16*   kb16 = (u16*)(ws + KB_OFF);
    float* qbuf = ws + QB_OFF;
    u16*   vb16 = (u16*)(ws + VB_OFF);
    float* atb  = ws + AT_OFF;
    u16*   wshQ = (u16*)(ws + WSHQ_OFF);

    detect_kernel<<<1, 256, 0, stream>>>((const u16*)d_in[0], flag);

    prep_kernel<<<262, 256, 0, stream>>>(
        d_in[1], d_in[3], d_in[2], d_in[4], d_in[5], d_in[6], d_in[7], d_in[8],
        wsh, wshQ, cbf, qbf, awf, abf, krw, krh, zbuf, flag);

    qkv_mfma_kernel <<<dim3(2, 256), 256, 0, stream>>>(d_in[0], wshQ, qbf, flag, kb16, qbuf, vb16);
    conv_mfma_kernel<<<dim3(2, 256), 256, 0, stream>>>(d_in[0], wsh, cbf, flag, d_out);
    attn_mfma_kernel<<<dim3(16, 64), 256, 0, stream>>>(kb16, qbuf, vb16, krw, krh, atb);
    proj_kernel     <<<2048,         256, 0, stream>>>(atb, awf, abf, flag, d_out);
}

// Round 7
// 167.039 us; speedup vs baseline: 1.0655x; 1.0223x over previous
//
#include <hip/hip_runtime.h>
#include <cstdint>

using u16 = unsigned short;
using u32 = uint32_t;

typedef __attribute__((ext_vector_type(8))) short bf16x8;   // 8 bf16 = 4 VGPRs
typedef __attribute__((ext_vector_type(4))) float f32x4;    // MFMA accumulator

__device__ __forceinline__ float bf2f(u16 v) { return __uint_as_float(((u32)v) << 16); }
__device__ __forceinline__ u16 f2bf(float f) {
    u32 u = __float_as_uint(f);
    u += 0x7fffu + ((u >> 16) & 1u);   // RNE
    return (u16)(u >> 16);
}
// Native bf16 conversion (RNE); compiler may fuse pairs into v_cvt_pk_bf16_f32.
__device__ __forceinline__ u16 bf16u(float f) {
#if defined(__BF16_MANT_DIG__)
    __bf16 h = (__bf16)f;
    return __builtin_bit_cast(u16, h);
#else
    return f2bf(f);
#endif
}
// Raw hardware exp2 (v_exp_f32). OCML's exp2f adds denormal-range scaffolding
// (~6 VALU ops); for softmax, flush-to-zero below 2^-126 is exactly right
// (those P contribute 0 to numerator and denominator). Overflow handled by
// the +80 cap at the call sites.
__device__ __forceinline__ float fexp2(float x) {
#if __has_builtin(__builtin_amdgcn_exp2f)
    return __builtin_amdgcn_exp2f(x);
#else
    float r; asm("v_exp_f32 %0, %1" : "=v"(r) : "v"(x)); return r;
#endif
}

// ---- workspace float offsets ----
#define FLAG_OFF 0
#define ZERO_OFF 8         // 16 floats of guaranteed zeros (written by prep)
#define WSH_OFF  2097168   // conv weight bf16 fragments: u16[442368] = 221184 f
#define AWF_OFF  2588688   // 4096
#define CBF_OFF  2592784   // 192
#define QBF_OFF  2592976   // 192
#define ABF_OFF  2593168   // 64
#define KRW_OFF  2593232   // 504
#define KRH_OFF  2593736   // 504
#define KB_OFF   2594240   // kbuf bf16: u16[524288] (uses half the slot)
#define QB_OFF   3118528   // qbuf f32: 524288
#define VB_OFF   3642816   // vbuf bf16: u16[524288]
#define AT_OFF   4167104   // 524288
#define WSHQ_OFF 9409984   // qkv weight bf16 fragments: u16[49152] = 24576 f

// ---------------------------------------------------------------------------
// Dtype sniffer (verified; returns 0 on this problem's fp32 inputs).
// ---------------------------------------------------------------------------
__global__ void detect_kernel(const u16* __restrict__ x, int* __restrict__ flag) {
    __shared__ int cnt;
    if (threadIdx.x == 0) cnt = 0;
    __syncthreads();
    int c = 0;
    #pragma unroll
    for (int k = 0; k < 16; k++) {
        u16 v = x[threadIdx.x * 16 + k];
        int e = (v >> 7) & 0xFF;
        c += (e >= 110 && e <= 140) ? 1 : 0;
    }
    atomicAdd(&cnt, c);
    __syncthreads();
    if (threadIdx.x == 0) *flag = (cnt > 3300) ? 1 : 0;   // 1 = bf16 inputs
}

// ---------------------------------------------------------------------------
// Merged prep: wshufC (blocks 0..215), wshufQ (216..239), small cvt (240..261).
// Bodies identical to the R11-verified kernels.  + zeros the 64B zbuf region.
// ---------------------------------------------------------------------------
__global__ __launch_bounds__(256) void prep_kernel(
    const void* __restrict__ cw, const void* __restrict__ qw,
    const void* __restrict__ cb, const void* __restrict__ qb,
    const void* __restrict__ aw, const void* __restrict__ ab,
    const void* __restrict__ kw_, const void* __restrict__ kh_,
    u16* __restrict__ wshC, u16* __restrict__ wshQ,
    float* __restrict__ cbf, float* __restrict__ qbf, float* __restrict__ awf,
    float* __restrict__ abf, float* __restrict__ krw, float* __restrict__ krh,
    float* __restrict__ zbuf, const int* __restrict__ flag)
{
    const int blk = blockIdx.x;
    const int fl = *flag;
    if (blk < 240) {                         // weight shuffles into B-fragment order
        const void* w; u16* o; int g;
        if (blk < 216) { w = cw; o = wshC; g = blk * 256 + threadIdx.x; }
        else           { w = qw; o = wshQ; g = (blk - 216) * 256 + threadIdx.x; }
        const int kk = g / 768, rem = g % 768;
        const int tile = rem >> 6, lane = rem & 63;
        const int n = tile * 16 + (lane & 15);
        u16 tmp[8];
        #pragma unroll
        for (int j = 0; j < 8; j++) {
            const size_t k = (size_t)(kk * 32 + ((lane >> 4) << 3) + j);
            tmp[j] = fl ? ((const u16*)w)[k * 192 + n]
                        : f2bf(((const float*)w)[k * 192 + n]);
        }
        *(uint4*)(o + (size_t)g * 8) = *(const uint4*)tmp;
    } else {                                 // small-tensor fp32 normalize
        const int gid = (blk - 240) * 256 + threadIdx.x;
        const void* src; float* dst; int e;
        if      (gid <  192) { src = cb;  dst = cbf; e = gid; }
        else if (gid <  384) { src = qb;  dst = qbf; e = gid - 192; }
        else if (gid < 4480) { src = aw;  dst = awf; e = gid - 384; }
        else if (gid < 4544) { src = ab;  dst = abf; e = gid - 4480; }
        else if (gid < 5048) { src = kw_; dst = krw; e = gid - 4544; }
        else if (gid < 5552) { src = kh_; dst = krh; e = gid - 5048; }
        else if (gid < 5568) { zbuf[gid - 5552] = 0.f; return; }
        else return;
        dst[e] = fl ? bf2f(((const u16*)src)[e]) : ((const float*)src)[e];
    }
}

// ---------------------------------------------------------------------------
// QKV implicit GEMM, bf16 MFMA (R10/R11-verified body). Epilogue change:
// k and v are written as bf16 (identical numerics — attn f2bf'd them anyway);
// q stays f32 with scale 8^-0.5 * log2(e).
// ---------------------------------------------------------------------------
__global__ __launch_bounds__(256) void qkv_mfma_kernel(
    const void* __restrict__ xr, const u16* __restrict__ wsh, const float* __restrict__ qbf_,
    const int* __restrict__ flag,
    u16* __restrict__ kb16, float* __restrict__ qbuf, u16* __restrict__ vb16)
{
    const int coh = blockIdx.x, row = blockIdx.y;
    const int b = row >> 5, h = row & 31;
    const int t = threadIdx.x;
    __shared__ u16 xs[32 * 264];                            // 16896 B
    const int fl = *flag;

    if (fl) {
        const u16* src = (const u16*)xr + (size_t)row * 8192;
        #pragma unroll
        for (int i = 0; i < 4; ++i) {
            const int idx = t + i * 256;
            const int px = idx >> 5, cq = idx & 31;
            *(uint4*)(xs + px * 264 + cq * 8) = *(const uint4*)(src + px * 256 + cq * 8);
        }
    } else {
        const float* src = (const float*)xr + (size_t)row * 8192;
        #pragma unroll
        for (int i = 0; i < 8; ++i) {
            const int idx = t + i * 256;
            const int px = idx >> 6, c4 = idx & 63;
            float4 v = *(const float4*)(src + px * 256 + c4 * 4);
            u32 lo = (u32)f2bf(v.x) | ((u32)f2bf(v.y) << 16);
            u32 hi = (u32)f2bf(v.z) | ((u32)f2bf(v.w) << 16);
            *(uint2*)(xs + px * 264 + c4 * 4) = make_uint2(lo, hi);
        }
    }
    __syncthreads();

    const int lane = t & 63, wave = t >> 6;
    const int Mtile = wave & 1;
    const int tg0 = coh * 6 + (wave >> 1) * 3;
    const int l15 = lane & 15, quad = lane >> 4;

    f32x4 acc[3] = {{0,0,0,0},{0,0,0,0},{0,0,0,0}};

    const u16* ap = xs + (Mtile * 16 + l15) * 264 + quad * 8;
    #pragma unroll
    for (int kk = 0; kk < 8; ++kk) {
        const bf16x8 av = *(const bf16x8*)(ap + kk * 32);
        const u16* wp = wsh + ((size_t)(kk * 12 + tg0) * 64 + lane) * 8;
        const bf16x8 b0 = *(const bf16x8*)(wp);
        const bf16x8 b1 = *(const bf16x8*)(wp + 512);
        const bf16x8 b2 = *(const bf16x8*)(wp + 1024);
        acc[0] = __builtin_amdgcn_mfma_f32_16x16x32_bf16(av, b0, acc[0], 0, 0, 0);
        acc[1] = __builtin_amdgcn_mfma_f32_16x16x32_bf16(av, b1, acc[1], 0, 0, 0);
        acc[2] = __builtin_amdgcn_mfma_f32_16x16x32_bf16(av, b2, acc[2], 0, 0, 0);
    }

    // D layout (verified): col = lane&15, row = quad*4 + reg
    const int px0 = Mtile * 16 + quad * 4;
    #pragma unroll
    for (int ti = 0; ti < 3; ++ti) {
        const int tg = tg0 + ti;
        const int o = tg * 16 + l15;
        const int third = tg >> 2;                          // 0=k,1=q,2=v (wave-uniform)
        const int within = o - third * 64;
        const int n = within >> 3, d = within & 7;
        const float bias = qbf_[o];
        #pragma unroll
        for (int r = 0; r < 4; ++r) {
            const int i = h * 32 + px0 + r;
            const size_t off = ((size_t)(b * 8 + n) * 1024 + i) * 8 + d;
            const float val = acc[ti][r] + bias;
            if (third == 0)      kb16[off] = f2bf(val);
            else if (third == 1) qbuf[off] = val * 0.51006973050f;  // 8^-.5 * log2e
            else                 vb16[off] = f2bf(val);
        }
    }
}

// ---------------------------------------------------------------------------
// Conv 3x3 implicit GEMM, bf16 MFMA. VERIFIED — unchanged.
// ---------------------------------------------------------------------------
__global__ __launch_bounds__(256) void conv_mfma_kernel(
    const void* __restrict__ xr, const u16* __restrict__ wsh, const float* __restrict__ cbf,
    const int* __restrict__ flag, void* __restrict__ out)
{
    const int coh = blockIdx.x, row = blockIdx.y;
    const int b = row >> 5, h = row & 31;
    const int t = threadIdx.x;
    __shared__ u16 xs[3 * 34 * 264];                        // 53856 B
    const int fl = *flag;

    #pragma unroll
    for (int r = 0; r < 3; ++r) {
        const int hh = h + r - 1;
        if (t < 64) {
            const int s = (t >> 5) ? 33 : 0, cq = t & 31;
            *(uint4*)(xs + (r * 34 + s) * 264 + cq * 8) = make_uint4(0, 0, 0, 0);
        }
        const bool ok = (hh >= 0) && (hh < 32);
        const size_t base = ((size_t)((b * 32 + (ok ? hh : 0)) * 32)) * 256;
        if (fl) {
            const u16* src = (const u16*)xr + base;
            #pragma unroll
            for (int i = 0; i < 4; ++i) {
                const int idx = t + i * 256;
                const int px = idx >> 5, cq = idx & 31;
                uint4 v = ok ? *(const uint4*)(src + px * 256 + cq * 8)
                             : make_uint4(0, 0, 0, 0);
                *(uint4*)(xs + (r * 34 + 1 + px) * 264 + cq * 8) = v;
            }
        } else {
            const float* src = (const float*)xr + base;
            #pragma unroll
            for (int i = 0; i < 8; ++i) {
                const int idx = t + i * 256;
                const int px = idx >> 6, c4 = idx & 63;
                float4 v = ok ? *(const float4*)(src + px * 256 + c4 * 4)
                              : make_float4(0.f, 0.f, 0.f, 0.f);
                u32 lo = (u32)f2bf(v.x) | ((u32)f2bf(v.y) << 16);
                u32 hi = (u32)f2bf(v.z) | ((u32)f2bf(v.w) << 16);
                *(uint2*)(xs + (r * 34 + 1 + px) * 264 + c4 * 4) = make_uint2(lo, hi);
            }
        }
    }
    __syncthreads();

    const int lane = t & 63, wave = t >> 6;
    const int Mtile = wave & 1;
    const int tg0 = coh * 6 + (wave >> 1) * 3;
    const int l15 = lane & 15, quad = lane >> 4;

    f32x4 acc[3] = {{0,0,0,0},{0,0,0,0},{0,0,0,0}};

    #pragma unroll
    for (int p = 0; p < 9; ++p) {
        const int kh = p / 3, kw = p - kh * 3;
        const u16* ap = xs + (kh * 34 + kw + Mtile * 16 + l15) * 264 + quad * 8;
        #pragma unroll
        for (int ck = 0; ck < 8; ++ck) {
            const int kk = p * 8 + ck;
            const bf16x8 av = *(const bf16x8*)(ap + ck * 32);
            const u16* wp = wsh + ((size_t)(kk * 12 + tg0) * 64 + lane) * 8;
            const bf16x8 b0 = *(const bf16x8*)(wp);
            const bf16x8 b1 = *(const bf16x8*)(wp + 512);
            const bf16x8 b2 = *(const bf16x8*)(wp + 1024);
            acc[0] = __builtin_amdgcn_mfma_f32_16x16x32_bf16(av, b0, acc[0], 0, 0, 0);
            acc[1] = __builtin_amdgcn_mfma_f32_16x16x32_bf16(av, b1, acc[1], 0, 0, 0);
            acc[2] = __builtin_amdgcn_mfma_f32_16x16x32_bf16(av, b2, acc[2], 0, 0, 0);
        }
    }

    const int px0 = Mtile * 16 + quad * 4;
    #pragma unroll
    for (int ti = 0; ti < 3; ++ti) {
        const int co = (tg0 + ti) * 16 + l15;
        const float bias = cbf[co];
        #pragma unroll
        for (int r = 0; r < 4; ++r) {
            const size_t oidx = ((size_t)row * 32 + px0 + r) * 256 + co;
            const float v = acc[ti][r] + bias;
            if (fl) ((u16*)out)[oidx] = f2bf(v);
            else    ((float*)out)[oidx] = v;
        }
    }
}

// ---------------------------------------------------------------------------
// MFMA flash attention v9 — identical to the R6-verified v8 structure
// (swapped QK^T, same-lane key partition, hoisted rel-W, split E/O PV
// accumulators, uniform broadcast K loads) with ONE change:
//   exp2f -> raw v_exp_f32 (fexp2).  OCML's exp2f emits ~6 VALU ops for
//   denormal-range handling; softmax wants flush-to-zero there anyway.
//   Cuts ~40 VALU ops per chunk (~35% of chunk-loop VALU issue).
// LDS: 16512 + 5120 + 8704 = 30336 B.
// ---------------------------------------------------------------------------
#define ATTN_STEP8(C, KA, KB, OACC)                                            \
  do {                                                                         \
    const int c_ = (C);                                                        \
    const float rhv = sRH[c_ * 68 + wave * 16 + l15];                          \
    f32x4 acc0, acc1;                                                          \
    acc0[0] = rhv + rw0[0]; acc0[1] = rhv + rw0[1];                            \
    acc0[2] = rhv + rw0[2]; acc0[3] = rhv + rw0[3];                            \
    acc1[0] = rhv + rw1[0]; acc1[1] = rhv + rw1[1];                            \
    acc1[2] = rhv + rw1[2]; acc1[3] = rhv + rw1[3];                            \
    acc0 = __builtin_amdgcn_mfma_f32_16x16x32_bf16(KA, Aq.v, acc0, 0, 0, 0);   \
    acc1 = __builtin_amdgcn_mfma_f32_16x16x32_bf16(KB, Aq.v, acc1, 0, 0, 0);   \
    if (c_ + 2 < 32) {            /* prefetch 2 chunks ahead (ping-pong) */    \
      KA = *(const bf16x8*)(kp0 + (c_ + 2) * 256);                             \
      KB = *(const bf16x8*)(kp1 + (c_ + 2) * 256);                             \
    }                                                                          \
    union { u16 a[8]; bf16x8 v; } pf;                                          \
    pf.a[0] = bf16u(fexp2(fminf(acc0[0], 80.0f)));                             \
    pf.a[1] = bf16u(fexp2(fminf(acc0[1], 80.0f)));                             \
    pf.a[2] = bf16u(fexp2(fminf(acc0[2], 80.0f)));                             \
    pf.a[3] = bf16u(fexp2(fminf(acc0[3], 80.0f)));                             \
    pf.a[4] = bf16u(fexp2(fminf(acc1[0], 80.0f)));                             \
    pf.a[5] = bf16u(fexp2(fminf(acc1[1], 80.0f)));                             \
    pf.a[6] = bf16u(fexp2(fminf(acc1[2], 80.0f)));                             \
    pf.a[7] = bf16u(fexp2(fminf(acc1[3], 80.0f)));                             \
    bf16x8 Av;                                                                 \
    if (l15 < 8) Av = *(const bf16x8*)(sVT + l15 * 1032 + c_ * 32 + quad * 8); \
    else         Av = ONE.v;                                                   \
    OACC = __builtin_amdgcn_mfma_f32_16x16x32_bf16(Av, pf.v, OACC, 0, 0, 0);   \
  } while (0)

__global__ __launch_bounds__(256) void attn_mfma_kernel(
    const u16* __restrict__ kb16, const float* __restrict__ qbuf, const u16* __restrict__ vb16,
    const float* __restrict__ krw, const float* __restrict__ krh,
    float* __restrict__ attnbuf)
{
    const int qb = blockIdx.x;           // 0..15 (64 q-rows each)
    const int bn = blockIdx.y;           // 0..63
    const int b = bn >> 3, hn = bn & 7;
    const int t = threadIdx.x;
    const int i0 = qb * 64;

    __shared__ __align__(16) u16   sVT[8 * 1032];   // [d][key] bf16 (pad)  16512 B
    __shared__ __align__(16) u16   sRW[64 * 40];    // [ilocal][wk] bf16     5120 B
    __shared__ __align__(16) float sRH[32 * 68];    // [hk][ilocal] f32      8704 B

    // ---- stage V^T from bf16 vbuf (no conversion) — verified ----
    const u16* vg = vb16 + (size_t)bn * 8192;
    #pragma unroll
    for (int k4 = 0; k4 < 4; k4++) {
        const int key = t + k4 * 256;                 // 0..1023
        uint4 vv = *(const uint4*)(vg + key * 8);
        sVT[0 * 1032 + key] = (u16)(vv.x);  sVT[1 * 1032 + key] = (u16)(vv.x >> 16);
        sVT[2 * 1032 + key] = (u16)(vv.y);  sVT[3 * 1032 + key] = (u16)(vv.y >> 16);
        sVT[4 * 1032 + key] = (u16)(vv.z);  sVT[5 * 1032 + key] = (u16)(vv.z >> 16);
        sVT[6 * 1032 + key] = (u16)(vv.w);  sVT[7 * 1032 + key] = (u16)(vv.w >> 16);
    }
    // ---- rel tables: rw (bf16) and rh (f32 C-init) — verified ----
    #pragma unroll
    for (int k8 = 0; k8 < 8; k8++) {
        const int idx = t + k8 * 256;                 // 0..2047
        const int il = idx >> 5, w = idx & 31;
        const int i = i0 + il;
        const float* q = qbuf + ((size_t)bn * 1024 + i) * 8;
        float4 qa = *(const float4*)q, qc = *(const float4*)(q + 4);
        const float* rp = krw + (size_t)(w - (i & 31) + 31) * 8;
        float4 ra = *(const float4*)rp, rc = *(const float4*)(rp + 4);
        sRW[il * 40 + w] = f2bf(qa.x*ra.x + qa.y*ra.y + qa.z*ra.z + qa.w*ra.w
                              + qc.x*rc.x + qc.y*rc.y + qc.z*rc.z + qc.w*rc.w);
        const float* hp = krh + (size_t)(w - (i >> 5) + 31) * 8;
        float4 ha = *(const float4*)hp, hc = *(const float4*)(hp + 4);
        sRH[w * 68 + il] = qa.x*ha.x + qa.y*ha.y + qa.z*ha.z + qa.w*ha.w
                         + qc.x*hc.x + qc.y*hc.y + qc.z*hc.z + qc.w*hc.w;
    }
    __syncthreads();

    const int lane = t & 63, wave = t >> 6;
    const int l15 = lane & 15, quad = lane >> 4;

    union Frag { u16 a[8]; bf16x8 v; };
    Frag Aq;                                   // Q fragment (B operand), verified load
    {
        const float* q = qbuf + ((size_t)bn * 1024 + i0 + wave * 16 + l15) * 8;
        float4 qa = *(const float4*)q, qc = *(const float4*)(q + 4);
        Aq.a[0] = f2bf(qa.x); Aq.a[1] = f2bf(qa.y); Aq.a[2] = f2bf(qa.z); Aq.a[3] = f2bf(qa.w);
        Aq.a[4] = f2bf(qc.x); Aq.a[5] = f2bf(qc.y); Aq.a[6] = f2bf(qc.z); Aq.a[7] = f2bf(qc.w);
        if (quad != 0) {
            #pragma unroll
            for (int j = 0; j < 8; j++) Aq.a[j] = 0;
        }
    }
    // RW fragment: same register content as the verified kernel; used as B.
    const bf16x8 Arw = *(const bf16x8*)(sRW + (wave * 16 + l15) * 40 + quad * 8);

    // Selector fragments (verified in v7): S0 -> k=pi0(l15), S1 -> k=pi1(l15).
    Frag S0, S1, ONE;
    #pragma unroll
    for (int j = 0; j < 8; j++) { S0.a[j] = 0; S1.a[j] = 0; ONE.a[j] = 0x3F80; }
    if (quad == (l15 >> 2)) {
        S0.a[l15 & 3]       = 0x3F80;
        S1.a[4 + (l15 & 3)] = 0x3F80;
    }

    // Hoisted rel-W results (chunk-invariant):
    //   rw0[r] = rw[q=l15][wk = 8*quad + r],  rw1[r] = rw[q=l15][8*quad+4+r]
    f32x4 zero4 = {0.f, 0.f, 0.f, 0.f};
    const f32x4 rw0 = __builtin_amdgcn_mfma_f32_16x16x32_bf16(S0.v, Arw, zero4, 0, 0, 0);
    const f32x4 rw1 = __builtin_amdgcn_mfma_f32_16x16x32_bf16(S1.v, Arw, zero4, 0, 0, 0);

    // K row pointers — uniform across quads (quads 1-3 rows are don't-care:
    // they multiply Aq's zero k-rows). 16 distinct rows per load -> broadcast.
    const u16* kg = kb16 + (size_t)bn * 8192;
    const int s = l15 >> 2, rr = l15 & 3;
    const u16* kp0 = kg + (size_t)(8 * s + rr) * 8;          // pi0 rows
    const u16* kp1 = kg + (size_t)(8 * s + 4 + rr) * 8;      // pi1 rows

    f32x4 oaccE = {0.f, 0.f, 0.f, 0.f};
    f32x4 oaccO = {0.f, 0.f, 0.f, 0.f};

    bf16x8 kAa = *(const bf16x8*)(kp0);
    bf16x8 kBa = *(const bf16x8*)(kp1);
    bf16x8 kAb = *(const bf16x8*)(kp0 + 256);
    bf16x8 kBb = *(const bf16x8*)(kp1 + 256);

    for (int c2 = 0; c2 < 32; c2 += 2) {
        ATTN_STEP8(c2,     kAa, kBa, oaccE);
        ATTN_STEP8(c2 + 1, kAb, kBb, oaccO);
    }

    f32x4 oacc;
    oacc[0] = oaccE[0] + oaccO[0];
    oacc[1] = oaccE[1] + oaccO[1];
    oacc[2] = oaccE[2] + oaccO[2];
    oacc[3] = oaccE[3] + oaccO[3];

    // D2[row][q=l15]: rows 0-7 = O^T[d][q] (quads 0,1), rows 8-15 = l[q].
    const float lr = __shfl(oacc[0], 32 + l15, 64);       // (l15, quad=2) row 8
    const float inv = 1.0f / fmaxf(lr, 1e-30f);
    if (quad < 2) {
        float4 o;
        o.x = oacc[0] * inv; o.y = oacc[1] * inv;
        o.z = oacc[2] * inv; o.w = oacc[3] * inv;
        *(float4*)(attnbuf + ((size_t)b * 1024 + i0 + wave * 16 + l15) * 64
                   + hn * 8 + quad * 4) = o;
    }
}

// ---------------------------------------------------------------------------
// Output projection (VERIFIED — unchanged).
// ---------------------------------------------------------------------------
__global__ __launch_bounds__(256) void proj_kernel(
    const float* __restrict__ attnbuf, const float* __restrict__ awf, const float* __restrict__ abf,
    const int* __restrict__ flag, void* __restrict__ out)
{
    const int g = blockIdx.x * 256 + threadIdx.x;
    const int px = g >> 6, o = g & 63;
    const float* ar = attnbuf + (size_t)px * 64;
    float acc = abf[o];
    #pragma unroll 8
    for (int c = 0; c < 64; c++) acc += ar[c] * awf[c * 64 + o];
    if (*flag) ((u16*)out)[(size_t)px * 256 + 192 + o] = f2bf(acc);
    else       ((float*)out)[(size_t)px * 256 + 192 + o] = acc;
}

// ---------------------------------------------------------------------------
extern "C" void kernel_launch(void* const* d_in, const int* in_sizes, int n_in,
                              void* d_out, int out_size, void* d_ws, size_t ws_size,
                              hipStream_t stream)
{
    float* ws = (float*)d_ws;
    int*   flag = (int*)(ws + FLAG_OFF);
    float* zbuf = ws + ZERO_OFF;
    u16*   wsh  = (u16*)(ws + WSH_OFF);
    float* awf  = ws + AWF_OFF;
    float* cbf  = ws + CBF_OFF;
    float* qbf  = ws + QBF_OFF;
    float* abf  = ws + ABF_OFF;
    float* krw  = ws + KRW_OFF;
    float* krh  = ws + KRH_OFF;
    u16*   kb16 = (u16*)(ws + KB_OFF);
    float* qbuf = ws + QB_OFF;
    u16*   vb16 = (u16*)(ws + VB_OFF);
    float* atb  = ws + AT_OFF;
    u16*   wshQ = (u16*)(ws + WSHQ_OFF);

    detect_kernel<<<1, 256, 0, stream>>>((const u16*)d_in[0], flag);

    prep_kernel<<<262, 256, 0, stream>>>(
        d_in[1], d_in[3], d_in[2], d_in[4], d_in[5], d_in[6], d_in[7], d_in[8],
        wsh, wshQ, cbf, qbf, awf, abf, krw, krh, zbuf, flag);

    qkv_mfma_kernel <<<dim3(2, 256), 256, 0, stream>>>(d_in[0], wshQ, qbf, flag, kb16, qbuf, vb16);
    conv_mfma_kernel<<<dim3(2, 256), 256, 0, stream>>>(d_in[0], wsh, cbf, flag, d_out);
    attn_mfma_kernel<<<dim3(16, 64), 256, 0, stream>>>(kb16, qbuf, vb16, krw, krh, atb);
    proj_kernel     <<<2048,         256, 0, stream>>>(atb, awf, abf, flag, d_out);
}

// Round 8
// 165.250 us; speedup vs baseline: 1.0770x; 1.0108x over previous
//
#include <hip/hip_runtime.h>
#include <cstdint>

using u16 = unsigned short;
using u32 = uint32_t;

typedef __attribute__((ext_vector_type(8))) short bf16x8;   // 8 bf16 = 4 VGPRs
typedef __attribute__((ext_vector_type(4))) float f32x4;    // MFMA accumulator

__device__ __forceinline__ float bf2f(u16 v) { return __uint_as_float(((u32)v) << 16); }
__device__ __forceinline__ u16 f2bf(float f) {
    u32 u = __float_as_uint(f);
    u += 0x7fffu + ((u >> 16) & 1u);   // RNE
    return (u16)(u >> 16);
}
// Native bf16 conversion (RNE); compiler may fuse pairs into v_cvt_pk_bf16_f32.
__device__ __forceinline__ u16 bf16u(float f) {
#if defined(__BF16_MANT_DIG__)
    __bf16 h = (__bf16)f;
    return __builtin_bit_cast(u16, h);
#else
    return f2bf(f);
#endif
}
// Raw hardware exp2 (v_exp_f32); flush-to-zero below 2^-126 is exactly right
// for softmax. Overflow handled by the +80 cap at call sites.
__device__ __forceinline__ float fexp2(float x) {
#if __has_builtin(__builtin_amdgcn_exp2f)
    return __builtin_amdgcn_exp2f(x);
#else
    float r; asm("v_exp_f32 %0, %1" : "=v"(r) : "v"(x)); return r;
#endif
}

// ---- workspace float offsets ----
#define FLAG_OFF 0
#define ZERO_OFF 8         // 16 floats of guaranteed zeros (written by prep)
#define WSH_OFF  2097168   // conv weight bf16 fragments: u16[442368] = 221184 f
#define AWF_OFF  2588688   // 4096
#define CBF_OFF  2592784   // 192
#define QBF_OFF  2592976   // 192
#define ABF_OFF  2593168   // 64
#define KRW_OFF  2593232   // 504
#define KRH_OFF  2593736   // 504
#define KB_OFF   2594240   // kbuf bf16: u16[524288] (uses half the slot)
#define QB_OFF   3118528   // qbuf f32: 524288
#define VB_OFF   3642816   // vbuf bf16: u16[524288]
#define AT_OFF   4167104   // 524288
#define XBF_OFF  4691392   // x as bf16: u16[2097152] = 1048576 f (4 MB)
#define WSHQ_OFF 9409984   // qkv weight bf16 fragments: u16[49152] = 24576 f

// ---------------------------------------------------------------------------
// Dtype sniffer (verified; returns 0 on this problem's fp32 inputs).
// ---------------------------------------------------------------------------
__global__ void detect_kernel(const u16* __restrict__ x, int* __restrict__ flag) {
    __shared__ int cnt;
    if (threadIdx.x == 0) cnt = 0;
    __syncthreads();
    int c = 0;
    #pragma unroll
    for (int k = 0; k < 16; k++) {
        u16 v = x[threadIdx.x * 16 + k];
        int e = (v >> 7) & 0xFF;
        c += (e >= 110 && e <= 140) ? 1 : 0;
    }
    atomicAdd(&cnt, c);
    __syncthreads();
    if (threadIdx.x == 0) *flag = (cnt > 3300) ? 1 : 0;   // 1 = bf16 inputs
}

// ---------------------------------------------------------------------------
// x -> bf16 pre-conversion (NEW): one streaming pass (read 8 MB f32 or copy
// 4 MB bf16, write 4 MB) so qkv/conv staging becomes pure uint4 copies.
// Same RNE f2bf the staging paths used -> bit-identical staged values.
// 1024 blocks x 256 threads, 8 elements/thread.
// ---------------------------------------------------------------------------
__global__ __launch_bounds__(256) void xcvt_kernel(
    const void* __restrict__ xr, u16* __restrict__ xbf, const int* __restrict__ flag)
{
    const int g = blockIdx.x * 256 + threadIdx.x;     // 0..262143
    if (*flag) {
        *(uint4*)(xbf + (size_t)g * 8) = *(const uint4*)((const u16*)xr + (size_t)g * 8);
    } else {
        const float* src = (const float*)xr + (size_t)g * 8;
        float4 a = *(const float4*)src, b = *(const float4*)(src + 4);
        uint4 o;
        o.x = (u32)f2bf(a.x) | ((u32)f2bf(a.y) << 16);
        o.y = (u32)f2bf(a.z) | ((u32)f2bf(a.w) << 16);
        o.z = (u32)f2bf(b.x) | ((u32)f2bf(b.y) << 16);
        o.w = (u32)f2bf(b.z) | ((u32)f2bf(b.w) << 16);
        *(uint4*)(xbf + (size_t)g * 8) = o;
    }
}

// ---------------------------------------------------------------------------
// Merged prep: wshufC (blocks 0..215), wshufQ (216..239), small cvt (240..261).
// Bodies identical to the R11-verified kernels.  + zeros the 64B zbuf region.
// ---------------------------------------------------------------------------
__global__ __launch_bounds__(256) void prep_kernel(
    const void* __restrict__ cw, const void* __restrict__ qw,
    const void* __restrict__ cb, const void* __restrict__ qb,
    const void* __restrict__ aw, const void* __restrict__ ab,
    const void* __restrict__ kw_, const void* __restrict__ kh_,
    u16* __restrict__ wshC, u16* __restrict__ wshQ,
    float* __restrict__ cbf, float* __restrict__ qbf, float* __restrict__ awf,
    float* __restrict__ abf, float* __restrict__ krw, float* __restrict__ krh,
    float* __restrict__ zbuf, const int* __restrict__ flag)
{
    const int blk = blockIdx.x;
    const int fl = *flag;
    if (blk < 240) {                         // weight shuffles into B-fragment order
        const void* w; u16* o; int g;
        if (blk < 216) { w = cw; o = wshC; g = blk * 256 + threadIdx.x; }
        else           { w = qw; o = wshQ; g = (blk - 216) * 256 + threadIdx.x; }
        const int kk = g / 768, rem = g % 768;
        const int tile = rem >> 6, lane = rem & 63;
        const int n = tile * 16 + (lane & 15);
        u16 tmp[8];
        #pragma unroll
        for (int j = 0; j < 8; j++) {
            const size_t k = (size_t)(kk * 32 + ((lane >> 4) << 3) + j);
            tmp[j] = fl ? ((const u16*)w)[k * 192 + n]
                        : f2bf(((const float*)w)[k * 192 + n]);
        }
        *(uint4*)(o + (size_t)g * 8) = *(const uint4*)tmp;
    } else {                                 // small-tensor fp32 normalize
        const int gid = (blk - 240) * 256 + threadIdx.x;
        const void* src; float* dst; int e;
        if      (gid <  192) { src = cb;  dst = cbf; e = gid; }
        else if (gid <  384) { src = qb;  dst = qbf; e = gid - 192; }
        else if (gid < 4480) { src = aw;  dst = awf; e = gid - 384; }
        else if (gid < 4544) { src = ab;  dst = abf; e = gid - 4480; }
        else if (gid < 5048) { src = kw_; dst = krw; e = gid - 4544; }
        else if (gid < 5552) { src = kh_; dst = krh; e = gid - 5048; }
        else if (gid < 5568) { zbuf[gid - 5552] = 0.f; return; }
        else return;
        dst[e] = fl ? bf2f(((const u16*)src)[e]) : ((const float*)src)[e];
    }
}

// ---------------------------------------------------------------------------
// QKV implicit GEMM, bf16 MFMA (verified body). Staging now reads the
// pre-converted xbf (pure uint4 copies — the verified fl=1 path, made
// unconditional). MFMA loop and epilogue unchanged.
// ---------------------------------------------------------------------------
__global__ __launch_bounds__(256) void qkv_mfma_kernel(
    const u16* __restrict__ xbf, const u16* __restrict__ wsh, const float* __restrict__ qbf_,
    u16* __restrict__ kb16, float* __restrict__ qbuf, u16* __restrict__ vb16)
{
    const int coh = blockIdx.x, row = blockIdx.y;
    const int b = row >> 5, h = row & 31;
    const int t = threadIdx.x;
    __shared__ u16 xs[32 * 264];                            // 16896 B

    {
        const u16* src = xbf + (size_t)row * 8192;
        #pragma unroll
        for (int i = 0; i < 4; ++i) {
            const int idx = t + i * 256;
            const int px = idx >> 5, cq = idx & 31;
            *(uint4*)(xs + px * 264 + cq * 8) = *(const uint4*)(src + px * 256 + cq * 8);
        }
    }
    __syncthreads();

    const int lane = t & 63, wave = t >> 6;
    const int Mtile = wave & 1;
    const int tg0 = coh * 6 + (wave >> 1) * 3;
    const int l15 = lane & 15, quad = lane >> 4;

    f32x4 acc[3] = {{0,0,0,0},{0,0,0,0},{0,0,0,0}};

    const u16* ap = xs + (Mtile * 16 + l15) * 264 + quad * 8;
    #pragma unroll
    for (int kk = 0; kk < 8; ++kk) {
        const bf16x8 av = *(const bf16x8*)(ap + kk * 32);
        const u16* wp = wsh + ((size_t)(kk * 12 + tg0) * 64 + lane) * 8;
        const bf16x8 b0 = *(const bf16x8*)(wp);
        const bf16x8 b1 = *(const bf16x8*)(wp + 512);
        const bf16x8 b2 = *(const bf16x8*)(wp + 1024);
        acc[0] = __builtin_amdgcn_mfma_f32_16x16x32_bf16(av, b0, acc[0], 0, 0, 0);
        acc[1] = __builtin_amdgcn_mfma_f32_16x16x32_bf16(av, b1, acc[1], 0, 0, 0);
        acc[2] = __builtin_amdgcn_mfma_f32_16x16x32_bf16(av, b2, acc[2], 0, 0, 0);
    }

    // D layout (verified): col = lane&15, row = quad*4 + reg
    const int px0 = Mtile * 16 + quad * 4;
    #pragma unroll
    for (int ti = 0; ti < 3; ++ti) {
        const int tg = tg0 + ti;
        const int o = tg * 16 + l15;
        const int third = tg >> 2;                          // 0=k,1=q,2=v (wave-uniform)
        const int within = o - third * 64;
        const int n = within >> 3, d = within & 7;
        const float bias = qbf_[o];
        #pragma unroll
        for (int r = 0; r < 4; ++r) {
            const int i = h * 32 + px0 + r;
            const size_t off = ((size_t)(b * 8 + n) * 1024 + i) * 8 + d;
            const float val = acc[ti][r] + bias;
            if (third == 0)      kb16[off] = f2bf(val);
            else if (third == 1) qbuf[off] = val * 0.51006973050f;  // 8^-.5 * log2e
            else                 vb16[off] = f2bf(val);
        }
    }
}

// ---------------------------------------------------------------------------
// Conv 3x3 implicit GEMM, bf16 MFMA (verified body). Staging now reads the
// pre-converted xbf (the verified fl=1 path, made unconditional): 12 uint4
// copies replace 24 float4 loads + ~720 conversion VALU ops per thread.
// ---------------------------------------------------------------------------
__global__ __launch_bounds__(256) void conv_mfma_kernel(
    const u16* __restrict__ xbf, const u16* __restrict__ wsh, const float* __restrict__ cbf,
    const int* __restrict__ flag, void* __restrict__ out)
{
    const int coh = blockIdx.x, row = blockIdx.y;
    const int b = row >> 5, h = row & 31;
    const int t = threadIdx.x;
    __shared__ u16 xs[3 * 34 * 264];                        // 53856 B
    const int fl = *flag;

    #pragma unroll
    for (int r = 0; r < 3; ++r) {
        const int hh = h + r - 1;
        if (t < 64) {
            const int s = (t >> 5) ? 33 : 0, cq = t & 31;
            *(uint4*)(xs + (r * 34 + s) * 264 + cq * 8) = make_uint4(0, 0, 0, 0);
        }
        const bool ok = (hh >= 0) && (hh < 32);
        const u16* src = xbf + ((size_t)((b * 32 + (ok ? hh : 0)) * 32)) * 256;
        #pragma unroll
        for (int i = 0; i < 4; ++i) {
            const int idx = t + i * 256;
            const int px = idx >> 5, cq = idx & 31;
            uint4 v = ok ? *(const uint4*)(src + px * 256 + cq * 8)
                         : make_uint4(0, 0, 0, 0);
            *(uint4*)(xs + (r * 34 + 1 + px) * 264 + cq * 8) = v;
        }
    }
    __syncthreads();

    const int lane = t & 63, wave = t >> 6;
    const int Mtile = wave & 1;
    const int tg0 = coh * 6 + (wave >> 1) * 3;
    const int l15 = lane & 15, quad = lane >> 4;

    f32x4 acc[3] = {{0,0,0,0},{0,0,0,0},{0,0,0,0}};

    #pragma unroll
    for (int p = 0; p < 9; ++p) {
        const int kh = p / 3, kw = p - kh * 3;
        const u16* ap = xs + (kh * 34 + kw + Mtile * 16 + l15) * 264 + quad * 8;
        #pragma unroll
        for (int ck = 0; ck < 8; ++ck) {
            const int kk = p * 8 + ck;
            const bf16x8 av = *(const bf16x8*)(ap + ck * 32);
            const u16* wp = wsh + ((size_t)(kk * 12 + tg0) * 64 + lane) * 8;
            const bf16x8 b0 = *(const bf16x8*)(wp);
            const bf16x8 b1 = *(const bf16x8*)(wp + 512);
            const bf16x8 b2 = *(const bf16x8*)(wp + 1024);
            acc[0] = __builtin_amdgcn_mfma_f32_16x16x32_bf16(av, b0, acc[0], 0, 0, 0);
            acc[1] = __builtin_amdgcn_mfma_f32_16x16x32_bf16(av, b1, acc[1], 0, 0, 0);
            acc[2] = __builtin_amdgcn_mfma_f32_16x16x32_bf16(av, b2, acc[2], 0, 0, 0);
        }
    }

    const int px0 = Mtile * 16 + quad * 4;
    #pragma unroll
    for (int ti = 0; ti < 3; ++ti) {
        const int co = (tg0 + ti) * 16 + l15;
        const float bias = cbf[co];
        #pragma unroll
        for (int r = 0; r < 4; ++r) {
            const size_t oidx = ((size_t)row * 32 + px0 + r) * 256 + co;
            const float v = acc[ti][r] + bias;
            if (fl) ((u16*)out)[oidx] = f2bf(v);
            else    ((float*)out)[oidx] = v;
        }
    }
}

// ---------------------------------------------------------------------------
// MFMA flash attention v9 — GREEN (R7-verified). Unchanged this round.
// ---------------------------------------------------------------------------
#define ATTN_STEP8(C, KA, KB, OACC)                                            \
  do {                                                                         \
    const int c_ = (C);                                                        \
    const float rhv = sRH[c_ * 68 + wave * 16 + l15];                          \
    f32x4 acc0, acc1;                                                          \
    acc0[0] = rhv + rw0[0]; acc0[1] = rhv + rw0[1];                            \
    acc0[2] = rhv + rw0[2]; acc0[3] = rhv + rw0[3];                            \
    acc1[0] = rhv + rw1[0]; acc1[1] = rhv + rw1[1];                            \
    acc1[2] = rhv + rw1[2]; acc1[3] = rhv + rw1[3];                            \
    acc0 = __builtin_amdgcn_mfma_f32_16x16x32_bf16(KA, Aq.v, acc0, 0, 0, 0);   \
    acc1 = __builtin_amdgcn_mfma_f32_16x16x32_bf16(KB, Aq.v, acc1, 0, 0, 0);   \
    if (c_ + 2 < 32) {            /* prefetch 2 chunks ahead (ping-pong) */    \
      KA = *(const bf16x8*)(kp0 + (c_ + 2) * 256);                             \
      KB = *(const bf16x8*)(kp1 + (c_ + 2) * 256);                             \
    }                                                                          \
    union { u16 a[8]; bf16x8 v; } pf;                                          \
    pf.a[0] = bf16u(fexp2(fminf(acc0[0], 80.0f)));                             \
    pf.a[1] = bf16u(fexp2(fminf(acc0[1], 80.0f)));                             \
    pf.a[2] = bf16u(fexp2(fminf(acc0[2], 80.0f)));                             \
    pf.a[3] = bf16u(fexp2(fminf(acc0[3], 80.0f)));                             \
    pf.a[4] = bf16u(fexp2(fminf(acc1[0], 80.0f)));                             \
    pf.a[5] = bf16u(fexp2(fminf(acc1[1], 80.0f)));                             \
    pf.a[6] = bf16u(fexp2(fminf(acc1[2], 80.0f)));                             \
    pf.a[7] = bf16u(fexp2(fminf(acc1[3], 80.0f)));                             \
    bf16x8 Av;                                                                 \
    if (l15 < 8) Av = *(const bf16x8*)(sVT + l15 * 1032 + c_ * 32 + quad * 8); \
    else         Av = ONE.v;                                                   \
    OACC = __builtin_amdgcn_mfma_f32_16x16x32_bf16(Av, pf.v, OACC, 0, 0, 0);   \
  } while (0)

__global__ __launch_bounds__(256) void attn_mfma_kernel(
    const u16* __restrict__ kb16, const float* __restrict__ qbuf, const u16* __restrict__ vb16,
    const float* __restrict__ krw, const float* __restrict__ krh,
    float* __restrict__ attnbuf)
{
    const int qb = blockIdx.x;           // 0..15 (64 q-rows each)
    const int bn = blockIdx.y;           // 0..63
    const int b = bn >> 3, hn = bn & 7;
    const int t = threadIdx.x;
    const int i0 = qb * 64;

    __shared__ __align__(16) u16   sVT[8 * 1032];   // [d][key] bf16 (pad)  16512 B
    __shared__ __align__(16) u16   sRW[64 * 40];    // [ilocal][wk] bf16     5120 B
    __shared__ __align__(16) float sRH[32 * 68];    // [hk][ilocal] f32      8704 B

    // ---- stage V^T from bf16 vbuf (no conversion) — verified ----
    const u16* vg = vb16 + (size_t)bn * 8192;
    #pragma unroll
    for (int k4 = 0; k4 < 4; k4++) {
        const int key = t + k4 * 256;                 // 0..1023
        uint4 vv = *(const uint4*)(vg + key * 8);
        sVT[0 * 1032 + key] = (u16)(vv.x);  sVT[1 * 1032 + key] = (u16)(vv.x >> 16);
        sVT[2 * 1032 + key] = (u16)(vv.y);  sVT[3 * 1032 + key] = (u16)(vv.y >> 16);
        sVT[4 * 1032 + key] = (u16)(vv.z);  sVT[5 * 1032 + key] = (u16)(vv.z >> 16);
        sVT[6 * 1032 + key] = (u16)(vv.w);  sVT[7 * 1032 + key] = (u16)(vv.w >> 16);
    }
    // ---- rel tables: rw (bf16) and rh (f32 C-init) — verified ----
    #pragma unroll
    for (int k8 = 0; k8 < 8; k8++) {
        const int idx = t + k8 * 256;                 // 0..2047
        const int il = idx >> 5, w = idx & 31;
        const int i = i0 + il;
        const float* q = qbuf + ((size_t)bn * 1024 + i) * 8;
        float4 qa = *(const float4*)q, qc = *(const float4*)(q + 4);
        const float* rp = krw + (size_t)(w - (i & 31) + 31) * 8;
        float4 ra = *(const float4*)rp, rc = *(const float4*)(rp + 4);
        sRW[il * 40 + w] = f2bf(qa.x*ra.x + qa.y*ra.y + qa.z*ra.z + qa.w*ra.w
                              + qc.x*rc.x + qc.y*rc.y + qc.z*rc.z + qc.w*rc.w);
        const float* hp = krh + (size_t)(w - (i >> 5) + 31) * 8;
        float4 ha = *(const float4*)hp, hc = *(const float4*)(hp + 4);
        sRH[w * 68 + il] = qa.x*ha.x + qa.y*ha.y + qa.z*ha.z + qa.w*ha.w
                         + qc.x*hc.x + qc.y*hc.y + qc.z*hc.z + qc.w*hc.w;
    }
    __syncthreads();

    const int lane = t & 63, wave = t >> 6;
    const int l15 = lane & 15, quad = lane >> 4;

    union Frag { u16 a[8]; bf16x8 v; };
    Frag Aq;                                   // Q fragment (B operand), verified load
    {
        const float* q = qbuf + ((size_t)bn * 1024 + i0 + wave * 16 + l15) * 8;
        float4 qa = *(const float4*)q, qc = *(const float4*)(q + 4);
        Aq.a[0] = f2bf(qa.x); Aq.a[1] = f2bf(qa.y); Aq.a[2] = f2bf(qa.z); Aq.a[3] = f2bf(qa.w);
        Aq.a[4] = f2bf(qc.x); Aq.a[5] = f2bf(qc.y); Aq.a[6] = f2bf(qc.z); Aq.a[7] = f2bf(qc.w);
        if (quad != 0) {
            #pragma unroll
            for (int j = 0; j < 8; j++) Aq.a[j] = 0;
        }
    }
    // RW fragment: same register content as the verified kernel; used as B.
    const bf16x8 Arw = *(const bf16x8*)(sRW + (wave * 16 + l15) * 40 + quad * 8);

    // Selector fragments (verified in v7): S0 -> k=pi0(l15), S1 -> k=pi1(l15).
    Frag S0, S1, ONE;
    #pragma unroll
    for (int j = 0; j < 8; j++) { S0.a[j] = 0; S1.a[j] = 0; ONE.a[j] = 0x3F80; }
    if (quad == (l15 >> 2)) {
        S0.a[l15 & 3]       = 0x3F80;
        S1.a[4 + (l15 & 3)] = 0x3F80;
    }

    // Hoisted rel-W results (chunk-invariant):
    //   rw0[r] = rw[q=l15][wk = 8*quad + r],  rw1[r] = rw[q=l15][8*quad+4+r]
    f32x4 zero4 = {0.f, 0.f, 0.f, 0.f};
    const f32x4 rw0 = __builtin_amdgcn_mfma_f32_16x16x32_bf16(S0.v, Arw, zero4, 0, 0, 0);
    const f32x4 rw1 = __builtin_amdgcn_mfma_f32_16x16x32_bf16(S1.v, Arw, zero4, 0, 0, 0);

    // K row pointers — uniform across quads (quads 1-3 rows are don't-care:
    // they multiply Aq's zero k-rows). 16 distinct rows per load -> broadcast.
    const u16* kg = kb16 + (size_t)bn * 8192;
    const int s = l15 >> 2, rr = l15 & 3;
    const u16* kp0 = kg + (size_t)(8 * s + rr) * 8;          // pi0 rows
    const u16* kp1 = kg + (size_t)(8 * s + 4 + rr) * 8;      // pi1 rows

    f32x4 oaccE = {0.f, 0.f, 0.f, 0.f};
    f32x4 oaccO = {0.f, 0.f, 0.f, 0.f};

    bf16x8 kAa = *(const bf16x8*)(kp0);
    bf16x8 kBa = *(const bf16x8*)(kp1);
    bf16x8 kAb = *(const bf16x8*)(kp0 + 256);
    bf16x8 kBb = *(const bf16x8*)(kp1 + 256);

    for (int c2 = 0; c2 < 32; c2 += 2) {
        ATTN_STEP8(c2,     kAa, kBa, oaccE);
        ATTN_STEP8(c2 + 1, kAb, kBb, oaccO);
    }

    f32x4 oacc;
    oacc[0] = oaccE[0] + oaccO[0];
    oacc[1] = oaccE[1] + oaccO[1];
    oacc[2] = oaccE[2] + oaccO[2];
    oacc[3] = oaccE[3] + oaccO[3];

    // D2[row][q=l15]: rows 0-7 = O^T[d][q] (quads 0,1), rows 8-15 = l[q].
    const float lr = __shfl(oacc[0], 32 + l15, 64);       // (l15, quad=2) row 8
    const float inv = 1.0f / fmaxf(lr, 1e-30f);
    if (quad < 2) {
        float4 o;
        o.x = oacc[0] * inv; o.y = oacc[1] * inv;
        o.z = oacc[2] * inv; o.w = oacc[3] * inv;
        *(float4*)(attnbuf + ((size_t)b * 1024 + i0 + wave * 16 + l15) * 64
                   + hn * 8 + quad * 4) = o;
    }
}

// ---------------------------------------------------------------------------
// Output projection (VERIFIED — unchanged).
// ---------------------------------------------------------------------------
__global__ __launch_bounds__(256) void proj_kernel(
    const float* __restrict__ attnbuf, const float* __restrict__ awf, const float* __restrict__ abf,
    const int* __restrict__ flag, void* __restrict__ out)
{
    const int g = blockIdx.x * 256 + threadIdx.x;
    const int px = g >> 6, o = g & 63;
    const float* ar = attnbuf + (size_t)px * 64;
    float acc = abf[o];
    #pragma unroll 8
    for (int c = 0; c < 64; c++) acc += ar[c] * awf[c * 64 + o];
    if (*flag) ((u16*)out)[(size_t)px * 256 + 192 + o] = f2bf(acc);
    else       ((float*)out)[(size_t)px * 256 + 192 + o] = acc;
}

// ---------------------------------------------------------------------------
extern "C" void kernel_launch(void* const* d_in, const int* in_sizes, int n_in,
                              void* d_out, int out_size, void* d_ws, size_t ws_size,
                              hipStream_t stream)
{
    float* ws = (float*)d_ws;
    int*   flag = (int*)(ws + FLAG_OFF);
    float* zbuf = ws + ZERO_OFF;
    u16*   wsh  = (u16*)(ws + WSH_OFF);
    float* awf  = ws + AWF_OFF;
    float* cbf  = ws + CBF_OFF;
    float* qbf  = ws + QBF_OFF;
    float* abf  = ws + ABF_OFF;
    float* krw  = ws + KRW_OFF;
    float* krh  = ws + KRH_OFF;
    u16*   kb16 = (u16*)(ws + KB_OFF);
    float* qbuf = ws + QB_OFF;
    u16*   vb16 = (u16*)(ws + VB_OFF);
    float* atb  = ws + AT_OFF;
    u16*   xbf  = (u16*)(ws + XBF_OFF);
    u16*   wshQ = (u16*)(ws + WSHQ_OFF);

    detect_kernel<<<1, 256, 0, stream>>>((const u16*)d_in[0], flag);

    prep_kernel<<<262, 256, 0, stream>>>(
        d_in[1], d_in[3], d_in[2], d_in[4], d_in[5], d_in[6], d_in[7], d_in[8],
        wsh, wshQ, cbf, qbf, awf, abf, krw, krh, zbuf, flag);

    xcvt_kernel<<<1024, 256, 0, stream>>>(d_in[0], xbf, flag);

    qkv_mfma_kernel <<<dim3(2, 256), 256, 0, stream>>>(xbf, wshQ, qbf, kb16, qbuf, vb16);
    conv_mfma_kernel<<<dim3(2, 256), 256, 0, stream>>>(xbf, wsh, cbf, flag, d_out);
    attn_mfma_kernel<<<dim3(16, 64), 256, 0, stream>>>(kb16, qbuf, vb16, krw, krh, atb);
    proj_kernel     <<<2048,         256, 0, stream>>>(atb, awf, abf, flag, d_out);
}

// Round 9
// 163.978 us; speedup vs baseline: 1.0854x; 1.0078x over previous
//
#include <hip/hip_runtime.h>
#include <cstdint>

using u16 = unsigned short;
using u32 = uint32_t;

typedef __attribute__((ext_vector_type(8))) short bf16x8;   // 8 bf16 = 4 VGPRs
typedef __attribute__((ext_vector_type(4))) float f32x4;    // MFMA accumulator

__device__ __forceinline__ float bf2f(u16 v) { return __uint_as_float(((u32)v) << 16); }
__device__ __forceinline__ u16 f2bf(float f) {
    u32 u = __float_as_uint(f);
    u += 0x7fffu + ((u >> 16) & 1u);   // RNE
    return (u16)(u >> 16);
}
// Native bf16 conversion (RNE); compiler may fuse pairs into v_cvt_pk_bf16_f32.
__device__ __forceinline__ u16 bf16u(float f) {
#if defined(__BF16_MANT_DIG__)
    __bf16 h = (__bf16)f;
    return __builtin_bit_cast(u16, h);
#else
    return f2bf(f);
#endif
}
// Raw hardware exp2 (v_exp_f32); flush-to-zero below 2^-126 is exactly right
// for softmax. Overflow handled by the +80 cap at call sites.
__device__ __forceinline__ float fexp2(float x) {
#if __has_builtin(__builtin_amdgcn_exp2f)
    return __builtin_amdgcn_exp2f(x);
#else
    float r; asm("v_exp_f32 %0, %1" : "=v"(r) : "v"(x)); return r;
#endif
}

// ---- workspace float offsets ----
#define FLAG_OFF 0
#define ZERO_OFF 8         // 16 floats of guaranteed zeros (written by prep)
#define WSH_OFF  2097168   // conv weight bf16 fragments: u16[442368] = 221184 f
#define AWF_OFF  2588688   // 4096
#define CBF_OFF  2592784   // 192
#define QBF_OFF  2592976   // 192
#define ABF_OFF  2593168   // 64
#define KRW_OFF  2593232   // 504
#define KRH_OFF  2593736   // 504
#define KB_OFF   2594240   // kbuf bf16: u16[524288] (uses half the slot)
#define QB_OFF   3118528   // qbuf f32: 524288
#define VB_OFF   3642816   // vbuf bf16: u16[524288]
#define AT_OFF   4167104   // 524288
#define XBF_OFF  4691392   // x as bf16: u16[2097152] = 1048576 f (4 MB)
#define WSHQ_OFF 9409984   // qkv weight bf16 fragments: u16[49152] = 24576 f

// ---------------------------------------------------------------------------
// Dtype sniffer (verified; returns 0 on this problem's fp32 inputs).
// ---------------------------------------------------------------------------
__global__ void detect_kernel(const u16* __restrict__ x, int* __restrict__ flag) {
    __shared__ int cnt;
    if (threadIdx.x == 0) cnt = 0;
    __syncthreads();
    int c = 0;
    #pragma unroll
    for (int k = 0; k < 16; k++) {
        u16 v = x[threadIdx.x * 16 + k];
        int e = (v >> 7) & 0xFF;
        c += (e >= 110 && e <= 140) ? 1 : 0;
    }
    atomicAdd(&cnt, c);
    __syncthreads();
    if (threadIdx.x == 0) *flag = (cnt > 3300) ? 1 : 0;   // 1 = bf16 inputs
}

// ---------------------------------------------------------------------------
// x -> bf16 pre-conversion (verified R8).
// ---------------------------------------------------------------------------
__global__ __launch_bounds__(256) void xcvt_kernel(
    const void* __restrict__ xr, u16* __restrict__ xbf, const int* __restrict__ flag)
{
    const int g = blockIdx.x * 256 + threadIdx.x;     // 0..262143
    if (*flag) {
        *(uint4*)(xbf + (size_t)g * 8) = *(const uint4*)((const u16*)xr + (size_t)g * 8);
    } else {
        const float* src = (const float*)xr + (size_t)g * 8;
        float4 a = *(const float4*)src, b = *(const float4*)(src + 4);
        uint4 o;
        o.x = (u32)f2bf(a.x) | ((u32)f2bf(a.y) << 16);
        o.y = (u32)f2bf(a.z) | ((u32)f2bf(a.w) << 16);
        o.z = (u32)f2bf(b.x) | ((u32)f2bf(b.y) << 16);
        o.w = (u32)f2bf(b.z) | ((u32)f2bf(b.w) << 16);
        *(uint4*)(xbf + (size_t)g * 8) = o;
    }
}

// ---------------------------------------------------------------------------
// Merged prep (verified). + zeros the 64B zbuf region.
// ---------------------------------------------------------------------------
__global__ __launch_bounds__(256) void prep_kernel(
    const void* __restrict__ cw, const void* __restrict__ qw,
    const void* __restrict__ cb, const void* __restrict__ qb,
    const void* __restrict__ aw, const void* __restrict__ ab,
    const void* __restrict__ kw_, const void* __restrict__ kh_,
    u16* __restrict__ wshC, u16* __restrict__ wshQ,
    float* __restrict__ cbf, float* __restrict__ qbf, float* __restrict__ awf,
    float* __restrict__ abf, float* __restrict__ krw, float* __restrict__ krh,
    float* __restrict__ zbuf, const int* __restrict__ flag)
{
    const int blk = blockIdx.x;
    const int fl = *flag;
    if (blk < 240) {                         // weight shuffles into B-fragment order
        const void* w; u16* o; int g;
        if (blk < 216) { w = cw; o = wshC; g = blk * 256 + threadIdx.x; }
        else           { w = qw; o = wshQ; g = (blk - 216) * 256 + threadIdx.x; }
        const int kk = g / 768, rem = g % 768;
        const int tile = rem >> 6, lane = rem & 63;
        const int n = tile * 16 + (lane & 15);
        u16 tmp[8];
        #pragma unroll
        for (int j = 0; j < 8; j++) {
            const size_t k = (size_t)(kk * 32 + ((lane >> 4) << 3) + j);
            tmp[j] = fl ? ((const u16*)w)[k * 192 + n]
                        : f2bf(((const float*)w)[k * 192 + n]);
        }
        *(uint4*)(o + (size_t)g * 8) = *(const uint4*)tmp;
    } else {                                 // small-tensor fp32 normalize
        const int gid = (blk - 240) * 256 + threadIdx.x;
        const void* src; float* dst; int e;
        if      (gid <  192) { src = cb;  dst = cbf; e = gid; }
        else if (gid <  384) { src = qb;  dst = qbf; e = gid - 192; }
        else if (gid < 4480) { src = aw;  dst = awf; e = gid - 384; }
        else if (gid < 4544) { src = ab;  dst = abf; e = gid - 4480; }
        else if (gid < 5048) { src = kw_; dst = krw; e = gid - 4544; }
        else if (gid < 5552) { src = kh_; dst = krh; e = gid - 5048; }
        else if (gid < 5568) { zbuf[gid - 5552] = 0.f; return; }
        else return;
        dst[e] = fl ? bf2f(((const u16*)src)[e]) : ((const float*)src)[e];
    }
}

// ---------------------------------------------------------------------------
// QKV implicit GEMM, bf16 MFMA (verified body, xbf staging).
// ---------------------------------------------------------------------------
__global__ __launch_bounds__(256) void qkv_mfma_kernel(
    const u16* __restrict__ xbf, const u16* __restrict__ wsh, const float* __restrict__ qbf_,
    u16* __restrict__ kb16, float* __restrict__ qbuf, u16* __restrict__ vb16)
{
    const int coh = blockIdx.x, row = blockIdx.y;
    const int b = row >> 5, h = row & 31;
    const int t = threadIdx.x;
    __shared__ u16 xs[32 * 264];                            // 16896 B

    {
        const u16* src = xbf + (size_t)row * 8192;
        #pragma unroll
        for (int i = 0; i < 4; ++i) {
            const int idx = t + i * 256;
            const int px = idx >> 5, cq = idx & 31;
            *(uint4*)(xs + px * 264 + cq * 8) = *(const uint4*)(src + px * 256 + cq * 8);
        }
    }
    __syncthreads();

    const int lane = t & 63, wave = t >> 6;
    const int Mtile = wave & 1;
    const int tg0 = coh * 6 + (wave >> 1) * 3;
    const int l15 = lane & 15, quad = lane >> 4;

    f32x4 acc[3] = {{0,0,0,0},{0,0,0,0},{0,0,0,0}};

    const u16* ap = xs + (Mtile * 16 + l15) * 264 + quad * 8;
    #pragma unroll
    for (int kk = 0; kk < 8; ++kk) {
        const bf16x8 av = *(const bf16x8*)(ap + kk * 32);
        const u16* wp = wsh + ((size_t)(kk * 12 + tg0) * 64 + lane) * 8;
        const bf16x8 b0 = *(const bf16x8*)(wp);
        const bf16x8 b1 = *(const bf16x8*)(wp + 512);
        const bf16x8 b2 = *(const bf16x8*)(wp + 1024);
        acc[0] = __builtin_amdgcn_mfma_f32_16x16x32_bf16(av, b0, acc[0], 0, 0, 0);
        acc[1] = __builtin_amdgcn_mfma_f32_16x16x32_bf16(av, b1, acc[1], 0, 0, 0);
        acc[2] = __builtin_amdgcn_mfma_f32_16x16x32_bf16(av, b2, acc[2], 0, 0, 0);
    }

    // D layout (verified): col = lane&15, row = quad*4 + reg
    const int px0 = Mtile * 16 + quad * 4;
    #pragma unroll
    for (int ti = 0; ti < 3; ++ti) {
        const int tg = tg0 + ti;
        const int o = tg * 16 + l15;
        const int third = tg >> 2;                          // 0=k,1=q,2=v (wave-uniform)
        const int within = o - third * 64;
        const int n = within >> 3, d = within & 7;
        const float bias = qbf_[o];
        #pragma unroll
        for (int r = 0; r < 4; ++r) {
            const int i = h * 32 + px0 + r;
            const size_t off = ((size_t)(b * 8 + n) * 1024 + i) * 8 + d;
            const float val = acc[ti][r] + bias;
            if (third == 0)      kb16[off] = f2bf(val);
            else if (third == 1) qbuf[off] = val * 0.51006973050f;  // 8^-.5 * log2e
            else                 vb16[off] = f2bf(val);
        }
    }
}

// ---------------------------------------------------------------------------
// Conv 3x3 implicit GEMM, bf16 MFMA (verified body, xbf staging).
// ---------------------------------------------------------------------------
__global__ __launch_bounds__(256) void conv_mfma_kernel(
    const u16* __restrict__ xbf, const u16* __restrict__ wsh, const float* __restrict__ cbf,
    const int* __restrict__ flag, void* __restrict__ out)
{
    const int coh = blockIdx.x, row = blockIdx.y;
    const int b = row >> 5, h = row & 31;
    const int t = threadIdx.x;
    __shared__ u16 xs[3 * 34 * 264];                        // 53856 B
    const int fl = *flag;

    #pragma unroll
    for (int r = 0; r < 3; ++r) {
        const int hh = h + r - 1;
        if (t < 64) {
            const int s = (t >> 5) ? 33 : 0, cq = t & 31;
            *(uint4*)(xs + (r * 34 + s) * 264 + cq * 8) = make_uint4(0, 0, 0, 0);
        }
        const bool ok = (hh >= 0) && (hh < 32);
        const u16* src = xbf + ((size_t)((b * 32 + (ok ? hh : 0)) * 32)) * 256;
        #pragma unroll
        for (int i = 0; i < 4; ++i) {
            const int idx = t + i * 256;
            const int px = idx >> 5, cq = idx & 31;
            uint4 v = ok ? *(const uint4*)(src + px * 256 + cq * 8)
                         : make_uint4(0, 0, 0, 0);
            *(uint4*)(xs + (r * 34 + 1 + px) * 264 + cq * 8) = v;
        }
    }
    __syncthreads();

    const int lane = t & 63, wave = t >> 6;
    const int Mtile = wave & 1;
    const int tg0 = coh * 6 + (wave >> 1) * 3;
    const int l15 = lane & 15, quad = lane >> 4;

    f32x4 acc[3] = {{0,0,0,0},{0,0,0,0},{0,0,0,0}};

    #pragma unroll
    for (int p = 0; p < 9; ++p) {
        const int kh = p / 3, kw = p - kh * 3;
        const u16* ap = xs + (kh * 34 + kw + Mtile * 16 + l15) * 264 + quad * 8;
        #pragma unroll
        for (int ck = 0; ck < 8; ++ck) {
            const int kk = p * 8 + ck;
            const bf16x8 av = *(const bf16x8*)(ap + ck * 32);
            const u16* wp = wsh + ((size_t)(kk * 12 + tg0) * 64 + lane) * 8;
            const bf16x8 b0 = *(const bf16x8*)(wp);
            const bf16x8 b1 = *(const bf16x8*)(wp + 512);
            const bf16x8 b2 = *(const bf16x8*)(wp + 1024);
            acc[0] = __builtin_amdgcn_mfma_f32_16x16x32_bf16(av, b0, acc[0], 0, 0, 0);
            acc[1] = __builtin_amdgcn_mfma_f32_16x16x32_bf16(av, b1, acc[1], 0, 0, 0);
            acc[2] = __builtin_amdgcn_mfma_f32_16x16x32_bf16(av, b2, acc[2], 0, 0, 0);
        }
    }

    const int px0 = Mtile * 16 + quad * 4;
    #pragma unroll
    for (int ti = 0; ti < 3; ++ti) {
        const int co = (tg0 + ti) * 16 + l15;
        const float bias = cbf[co];
        #pragma unroll
        for (int r = 0; r < 4; ++r) {
            const size_t oidx = ((size_t)row * 32 + px0 + r) * 256 + co;
            const float v = acc[ti][r] + bias;
            if (fl) ((u16*)out)[oidx] = f2bf(v);
            else    ((float*)out)[oidx] = v;
        }
    }
}

// ---------------------------------------------------------------------------
// MFMA flash attention v10 — v9's verified machinery, key-split across waves:
//   grid (32, 64): 32 q-rows per block; wave pair = wave>>1 owns 16 q-rows,
//   sub = wave&1 processes even/odd chunks (16 each). 2048 blocks, LDS
//   25.7 KB -> 6 blocks/CU resident = 24 waves/CU (was 16), and each wave's
//   serial chunk chain halves. Partial O/l sums add linearly (no max
//   tracking) -> sub==1 writes partials to LDS, sub==0 reduces + stores.
// ---------------------------------------------------------------------------
#define ATTN_STEPA(C, KA, KB, OACC)                                            \
  do {                                                                         \
    const int c_ = (C);                                                        \
    const float rhv = sRH[c_ * 36 + pair * 16 + l15];                          \
    f32x4 acc0, acc1;                                                          \
    acc0[0] = rhv + rw0[0]; acc0[1] = rhv + rw0[1];                            \
    acc0[2] = rhv + rw0[2]; acc0[3] = rhv + rw0[3];                            \
    acc1[0] = rhv + rw1[0]; acc1[1] = rhv + rw1[1];                            \
    acc1[2] = rhv + rw1[2]; acc1[3] = rhv + rw1[3];                            \
    acc0 = __builtin_amdgcn_mfma_f32_16x16x32_bf16(KA, Aq.v, acc0, 0, 0, 0);   \
    acc1 = __builtin_amdgcn_mfma_f32_16x16x32_bf16(KB, Aq.v, acc1, 0, 0, 0);   \
    if (c_ + 4 < 32) {            /* prefetch 4 chunks ahead (ping-pong) */    \
      KA = *(const bf16x8*)(kp0 + (c_ + 4) * 256);                             \
      KB = *(const bf16x8*)(kp1 + (c_ + 4) * 256);                             \
    }                                                                          \
    union { u16 a[8]; bf16x8 v; } pf;                                          \
    pf.a[0] = bf16u(fexp2(fminf(acc0[0], 80.0f)));                             \
    pf.a[1] = bf16u(fexp2(fminf(acc0[1], 80.0f)));                             \
    pf.a[2] = bf16u(fexp2(fminf(acc0[2], 80.0f)));                             \
    pf.a[3] = bf16u(fexp2(fminf(acc0[3], 80.0f)));                             \
    pf.a[4] = bf16u(fexp2(fminf(acc1[0], 80.0f)));                             \
    pf.a[5] = bf16u(fexp2(fminf(acc1[1], 80.0f)));                             \
    pf.a[6] = bf16u(fexp2(fminf(acc1[2], 80.0f)));                             \
    pf.a[7] = bf16u(fexp2(fminf(acc1[3], 80.0f)));                             \
    bf16x8 Av;                                                                 \
    if (l15 < 8) Av = *(const bf16x8*)(sVT + l15 * 1032 + c_ * 32 + quad * 8); \
    else         Av = ONE.v;                                                   \
    OACC = __builtin_amdgcn_mfma_f32_16x16x32_bf16(Av, pf.v, OACC, 0, 0, 0);   \
  } while (0)

__global__ __launch_bounds__(256) void attn_mfma_kernel(
    const u16* __restrict__ kb16, const float* __restrict__ qbuf, const u16* __restrict__ vb16,
    const float* __restrict__ krw, const float* __restrict__ krh,
    float* __restrict__ attnbuf)
{
    const int qb = blockIdx.x;           // 0..31 (32 q-rows each)
    const int bn = blockIdx.y;           // 0..63
    const int b = bn >> 3, hn = bn & 7;
    const int t = threadIdx.x;
    const int i0 = qb * 32;

    __shared__ __align__(16) u16   sVT[8 * 1032];   // [d][key] bf16 (pad)  16512 B
    __shared__ __align__(16) u16   sRW[32 * 40];    // [ilocal][wk] bf16     2560 B
    __shared__ __align__(16) float sRH[32 * 36];    // [hk][ilocal] f32      4608 B
    __shared__ __align__(16) float sRed[2 * 64 * 4];// pair partials         2048 B

    // ---- stage V^T from bf16 vbuf (no conversion) — verified ----
    const u16* vg = vb16 + (size_t)bn * 8192;
    #pragma unroll
    for (int k4 = 0; k4 < 4; k4++) {
        const int key = t + k4 * 256;                 // 0..1023
        uint4 vv = *(const uint4*)(vg + key * 8);
        sVT[0 * 1032 + key] = (u16)(vv.x);  sVT[1 * 1032 + key] = (u16)(vv.x >> 16);
        sVT[2 * 1032 + key] = (u16)(vv.y);  sVT[3 * 1032 + key] = (u16)(vv.y >> 16);
        sVT[4 * 1032 + key] = (u16)(vv.z);  sVT[5 * 1032 + key] = (u16)(vv.z >> 16);
        sVT[6 * 1032 + key] = (u16)(vv.w);  sVT[7 * 1032 + key] = (u16)(vv.w >> 16);
    }
    // ---- rel tables (verified math; 32 q-rows now) ----
    #pragma unroll
    for (int k8 = 0; k8 < 4; k8++) {
        const int idx = t + k8 * 256;                 // 0..1023
        const int il = idx >> 5, w = idx & 31;        // il 0..31
        const int i = i0 + il;
        const float* q = qbuf + ((size_t)bn * 1024 + i) * 8;
        float4 qa = *(const float4*)q, qc = *(const float4*)(q + 4);
        const float* rp = krw + (size_t)(w - (i & 31) + 31) * 8;
        float4 ra = *(const float4*)rp, rc = *(const float4*)(rp + 4);
        sRW[il * 40 + w] = f2bf(qa.x*ra.x + qa.y*ra.y + qa.z*ra.z + qa.w*ra.w
                              + qc.x*rc.x + qc.y*rc.y + qc.z*rc.z + qc.w*rc.w);
        const float* hp = krh + (size_t)(w - (i >> 5) + 31) * 8;
        float4 ha = *(const float4*)hp, hc = *(const float4*)(hp + 4);
        sRH[w * 36 + il] = qa.x*ha.x + qa.y*ha.y + qa.z*ha.z + qa.w*ha.w
                         + qc.x*hc.x + qc.y*hc.y + qc.z*hc.z + qc.w*hc.w;
    }
    __syncthreads();

    const int lane = t & 63, wave = t >> 6;
    const int pair = wave >> 1, sub = wave & 1;
    const int l15 = lane & 15, quad = lane >> 4;

    union Frag { u16 a[8]; bf16x8 v; };
    Frag Aq;                                   // Q fragment (B operand)
    {
        const float* q = qbuf + ((size_t)bn * 1024 + i0 + pair * 16 + l15) * 8;
        float4 qa = *(const float4*)q, qc = *(const float4*)(q + 4);
        Aq.a[0] = f2bf(qa.x); Aq.a[1] = f2bf(qa.y); Aq.a[2] = f2bf(qa.z); Aq.a[3] = f2bf(qa.w);
        Aq.a[4] = f2bf(qc.x); Aq.a[5] = f2bf(qc.y); Aq.a[6] = f2bf(qc.z); Aq.a[7] = f2bf(qc.w);
        if (quad != 0) {
            #pragma unroll
            for (int j = 0; j < 8; j++) Aq.a[j] = 0;
        }
    }
    const bf16x8 Arw = *(const bf16x8*)(sRW + (pair * 16 + l15) * 40 + quad * 8);

    // Selector fragments (verified): S0 -> k=pi0(l15), S1 -> k=pi1(l15).
    Frag S0, S1, ONE;
    #pragma unroll
    for (int j = 0; j < 8; j++) { S0.a[j] = 0; S1.a[j] = 0; ONE.a[j] = 0x3F80; }
    if (quad == (l15 >> 2)) {
        S0.a[l15 & 3]       = 0x3F80;
        S1.a[4 + (l15 & 3)] = 0x3F80;
    }

    // Hoisted rel-W results (chunk-invariant).
    f32x4 zero4 = {0.f, 0.f, 0.f, 0.f};
    const f32x4 rw0 = __builtin_amdgcn_mfma_f32_16x16x32_bf16(S0.v, Arw, zero4, 0, 0, 0);
    const f32x4 rw1 = __builtin_amdgcn_mfma_f32_16x16x32_bf16(S1.v, Arw, zero4, 0, 0, 0);

    // K row pointers — uniform across quads (verified).
    const u16* kg = kb16 + (size_t)bn * 8192;
    const int s = l15 >> 2, rr = l15 & 3;
    const u16* kp0 = kg + (size_t)(8 * s + rr) * 8;          // pi0 rows
    const u16* kp1 = kg + (size_t)(8 * s + 4 + rr) * 8;      // pi1 rows

    f32x4 oaccE = {0.f, 0.f, 0.f, 0.f};
    f32x4 oaccO = {0.f, 0.f, 0.f, 0.f};

    // This wave's chunks: sub, sub+2, ..., sub+30 (16 chunks).
    bf16x8 kAa = *(const bf16x8*)(kp0 + sub * 256);
    bf16x8 kBa = *(const bf16x8*)(kp1 + sub * 256);
    bf16x8 kAb = *(const bf16x8*)(kp0 + (sub + 2) * 256);
    bf16x8 kBb = *(const bf16x8*)(kp1 + (sub + 2) * 256);

    for (int c2 = sub; c2 < 32; c2 += 4) {
        ATTN_STEPA(c2,     kAa, kBa, oaccE);
        ATTN_STEPA(c2 + 2, kAb, kBb, oaccO);
    }

    f32x4 oacc;
    oacc[0] = oaccE[0] + oaccO[0];
    oacc[1] = oaccE[1] + oaccO[1];
    oacc[2] = oaccE[2] + oaccO[2];
    oacc[3] = oaccE[3] + oaccO[3];

    // Pair reduction: sub==1 writes partials; sub==0 adds.
    if (sub == 1) *(f32x4*)(sRed + (pair * 64 + lane) * 4) = oacc;
    __syncthreads();
    if (sub == 0) {
        const f32x4 part = *(const f32x4*)(sRed + (pair * 64 + lane) * 4);
        oacc[0] += part[0]; oacc[1] += part[1];
        oacc[2] += part[2]; oacc[3] += part[3];

        // D2[row][q=l15]: rows 0-7 = O^T[d][q] (quads 0,1), rows 8-15 = l[q].
        const float lr = __shfl(oacc[0], 32 + l15, 64);   // (l15, quad=2) row 8
        const float inv = 1.0f / fmaxf(lr, 1e-30f);
        if (quad < 2) {
            float4 o;
            o.x = oacc[0] * inv; o.y = oacc[1] * inv;
            o.z = oacc[2] * inv; o.w = oacc[3] * inv;
            *(float4*)(attnbuf + ((size_t)b * 1024 + i0 + pair * 16 + l15) * 64
                       + hn * 8 + quad * 4) = o;
        }
    }
}

// ---------------------------------------------------------------------------
// Output projection (VERIFIED — unchanged).
// ---------------------------------------------------------------------------
__global__ __launch_bounds__(256) void proj_kernel(
    const float* __restrict__ attnbuf, const float* __restrict__ awf, const float* __restrict__ abf,
    const int* __restrict__ flag, void* __restrict__ out)
{
    const int g = blockIdx.x * 256 + threadIdx.x;
    const int px = g >> 6, o = g & 63;
    const float* ar = attnbuf + (size_t)px * 64;
    float acc = abf[o];
    #pragma unroll 8
    for (int c = 0; c < 64; c++) acc += ar[c] * awf[c * 64 + o];
    if (*flag) ((u16*)out)[(size_t)px * 256 + 192 + o] = f2bf(acc);
    else       ((float*)out)[(size_t)px * 256 + 192 + o] = acc;
}

// ---------------------------------------------------------------------------
extern "C" void kernel_launch(void* const* d_in, const int* in_sizes, int n_in,
                              void* d_out, int out_size, void* d_ws, size_t ws_size,
                              hipStream_t stream)
{
    float* ws = (float*)d_ws;
    int*   flag = (int*)(ws + FLAG_OFF);
    float* zbuf = ws + ZERO_OFF;
    u16*   wsh  = (u16*)(ws + WSH_OFF);
    float* awf  = ws + AWF_OFF;
    float* cbf  = ws + CBF_OFF;
    float* qbf  = ws + QBF_OFF;
    float* abf  = ws + ABF_OFF;
    float* krw  = ws + KRW_OFF;
    float* krh  = ws + KRH_OFF;
    u16*   kb16 = (u16*)(ws + KB_OFF);
    float* qbuf = ws + QB_OFF;
    u16*   vb16 = (u16*)(ws + VB_OFF);
    float* atb  = ws + AT_OFF;
    u16*   xbf  = (u16*)(ws + XBF_OFF);
    u16*   wshQ = (u16*)(ws + WSHQ_OFF);

    detect_kernel<<<1, 256, 0, stream>>>((const u16*)d_in[0], flag);

    prep_kernel<<<262, 256, 0, stream>>>(
        d_in[1], d_in[3], d_in[2], d_in[4], d_in[5], d_in[6], d_in[7], d_in[8],
        wsh, wshQ, cbf, qbf, awf, abf, krw, krh, zbuf, flag);

    xcvt_kernel<<<1024, 256, 0, stream>>>(d_in[0], xbf, flag);

    qkv_mfma_kernel <<<dim3(2, 256), 256, 0, stream>>>(xbf, wshQ, qbf, kb16, qbuf, vb16);
    conv_mfma_kernel<<<dim3(2, 256), 256, 0, stream>>>(xbf, wsh, cbf, flag, d_out);
    attn_mfma_kernel<<<dim3(32, 64), 256, 0, stream>>>(kb16, qbuf, vb16, krw, krh, atb);
    proj_kernel     <<<2048,         256, 0, stream>>>(atb, awf, abf, flag, d_out);
}

// Round 10
// 147.213 us; speedup vs baseline: 1.2090x; 1.1139x over previous
//
#include <hip/hip_runtime.h>
#include <cstdint>

using u16 = unsigned short;
using u32 = uint32_t;

typedef __attribute__((ext_vector_type(8))) short bf16x8;   // 8 bf16 = 4 VGPRs
typedef __attribute__((ext_vector_type(4))) float f32x4;    // MFMA accumulator

__device__ __forceinline__ float bf2f(u16 v) { return __uint_as_float(((u32)v) << 16); }
__device__ __forceinline__ u16 f2bf(float f) {
    u32 u = __float_as_uint(f);
    u += 0x7fffu + ((u >> 16) & 1u);   // RNE
    return (u16)(u >> 16);
}
// Native bf16 conversion (RNE); compiler may fuse pairs into v_cvt_pk_bf16_f32.
__device__ __forceinline__ u16 bf16u(float f) {
#if defined(__BF16_MANT_DIG__)
    __bf16 h = (__bf16)f;
    return __builtin_bit_cast(u16, h);
#else
    return f2bf(f);
#endif
}
// Raw hardware exp2 (v_exp_f32); flush-to-zero below 2^-126 is exactly right
// for softmax. Overflow handled by the +80 cap at call sites.
__device__ __forceinline__ float fexp2(float x) {
#if __has_builtin(__builtin_amdgcn_exp2f)
    return __builtin_amdgcn_exp2f(x);
#else
    float r; asm("v_exp_f32 %0, %1" : "=v"(r) : "v"(x)); return r;
#endif
}

// Per-block dtype sniff (identical logic to the verified detect_kernel; every
// block sees the same first 4096 u16 of x -> identical result, deterministic).
__device__ __forceinline__ int block_flag(const u16* __restrict__ x) {
    __shared__ int cnt;
    if (threadIdx.x == 0) cnt = 0;
    __syncthreads();
    int c = 0;
    #pragma unroll
    for (int k = 0; k < 16; k++) {
        u16 v = x[threadIdx.x * 16 + k];
        int e = (v >> 7) & 0xFF;
        c += (e >= 110 && e <= 140) ? 1 : 0;
    }
    atomicAdd(&cnt, c);
    __syncthreads();
    return (cnt > 3300) ? 1 : 0;
}

// ---- workspace float offsets ----
#define FLAG_OFF 0
#define ZERO_OFF 8         // 16 floats of guaranteed zeros
#define WSH_OFF  2097168   // conv weight bf16 fragments: u16[442368] = 221184 f
#define AWF_OFF  2588688   // 4096
#define CBF_OFF  2592784   // 192
#define QBF_OFF  2592976   // 192
#define ABF_OFF  2593168   // 64
#define KRW_OFF  2593232   // 504
#define KRH_OFF  2593736   // 504
#define KB_OFF   2594240   // kbuf bf16: u16[524288] (uses half the slot)
#define QB_OFF   3118528   // qbuf f32: 524288
#define VB_OFF   3642816   // vbuf bf16: u16[524288]
#define AT_OFF   4167104   // 524288
#define XBF_OFF  4691392   // x as bf16: u16[2097152] = 1048576 f (4 MB)
#define WSHQ_OFF 9409984   // qkv weight bf16 fragments: u16[49152] = 24576 f

// ---------------------------------------------------------------------------
// prepx: merged detect + prep + xcvt (R8/R9-verified bodies, re-dispatched).
//   blocks 0..215   : conv weight shuffle
//   blocks 216..239 : qkv weight shuffle
//   blocks 240..261 : small-tensor fp32 normalize (+zbuf)
//   blocks 262..1285: x -> bf16 conversion (xcvt)
// Each block computes the dtype flag inline; block 0 persists it to ws.
// ---------------------------------------------------------------------------
__global__ __launch_bounds__(256) void prepx_kernel(
    const u16* __restrict__ x0,
    const void* __restrict__ cw, const void* __restrict__ qw,
    const void* __restrict__ cb, const void* __restrict__ qb,
    const void* __restrict__ aw, const void* __restrict__ ab,
    const void* __restrict__ kw_, const void* __restrict__ kh_,
    u16* __restrict__ wshC, u16* __restrict__ wshQ,
    float* __restrict__ cbf, float* __restrict__ qbf, float* __restrict__ awf,
    float* __restrict__ abf, float* __restrict__ krw, float* __restrict__ krh,
    float* __restrict__ zbuf, int* __restrict__ flagws, u16* __restrict__ xbf)
{
    const int blk = blockIdx.x;
    const int fl = block_flag(x0);
    if (blk == 0 && threadIdx.x == 0) *flagws = fl;

    if (blk < 240) {                         // weight shuffles into B-fragment order
        const void* w; u16* o; int g;
        if (blk < 216) { w = cw; o = wshC; g = blk * 256 + threadIdx.x; }
        else           { w = qw; o = wshQ; g = (blk - 216) * 256 + threadIdx.x; }
        const int kk = g / 768, rem = g % 768;
        const int tile = rem >> 6, lane = rem & 63;
        const int n = tile * 16 + (lane & 15);
        u16 tmp[8];
        #pragma unroll
        for (int j = 0; j < 8; j++) {
            const size_t k = (size_t)(kk * 32 + ((lane >> 4) << 3) + j);
            tmp[j] = fl ? ((const u16*)w)[k * 192 + n]
                        : f2bf(((const float*)w)[k * 192 + n]);
        }
        *(uint4*)(o + (size_t)g * 8) = *(const uint4*)tmp;
    } else if (blk < 262) {                  // small-tensor fp32 normalize
        const int gid = (blk - 240) * 256 + threadIdx.x;
        const void* src; float* dst; int e;
        if      (gid <  192) { src = cb;  dst = cbf; e = gid; }
        else if (gid <  384) { src = qb;  dst = qbf; e = gid - 192; }
        else if (gid < 4480) { src = aw;  dst = awf; e = gid - 384; }
        else if (gid < 4544) { src = ab;  dst = abf; e = gid - 4480; }
        else if (gid < 5048) { src = kw_; dst = krw; e = gid - 4544; }
        else if (gid < 5552) { src = kh_; dst = krh; e = gid - 5048; }
        else if (gid < 5568) { zbuf[gid - 5552] = 0.f; return; }
        else return;
        dst[e] = fl ? bf2f(((const u16*)src)[e]) : ((const float*)src)[e];
    } else {                                 // xcvt: x -> bf16 (verified R8)
        const int g = (blk - 262) * 256 + threadIdx.x;     // 0..262143
        if (fl) {
            *(uint4*)(xbf + (size_t)g * 8) = *(const uint4*)(x0 + (size_t)g * 8);
        } else {
            const float* src = (const float*)x0 + (size_t)g * 8;
            float4 a = *(const float4*)src, b = *(const float4*)(src + 4);
            uint4 o;
            o.x = (u32)f2bf(a.x) | ((u32)f2bf(a.y) << 16);
            o.y = (u32)f2bf(a.z) | ((u32)f2bf(a.w) << 16);
            o.z = (u32)f2bf(b.x) | ((u32)f2bf(b.y) << 16);
            o.w = (u32)f2bf(b.z) | ((u32)f2bf(b.w) << 16);
            *(uint4*)(xbf + (size_t)g * 8) = o;
        }
    }
}

// ---------------------------------------------------------------------------
// qc: merged conv (blocks 0..511) + qkv (blocks 512..1023). Both bodies are
// the R8/R9-verified ones, unchanged; qkv now executes in conv's occupancy
// shadow instead of serially after it. Shared LDS block sized for conv.
// ---------------------------------------------------------------------------
__global__ __launch_bounds__(256) void qc_kernel(
    const u16* __restrict__ xbf, const u16* __restrict__ wshC, const u16* __restrict__ wshQ,
    const float* __restrict__ cbf, const float* __restrict__ qbf_,
    const int* __restrict__ flagws,
    u16* __restrict__ kb16, float* __restrict__ qbuf, u16* __restrict__ vb16,
    void* __restrict__ out)
{
    __shared__ u16 xs[3 * 34 * 264];                        // 53856 B (conv size)
    const int blk = blockIdx.x;
    const int t = threadIdx.x;
    const int lane = t & 63, wave = t >> 6;
    const int Mtile = wave & 1;
    const int l15 = lane & 15, quad = lane >> 4;

    if (blk < 512) {
        // ================= conv role (verified body) =================
        const int coh = blk & 1, row = blk >> 1;
        const int b = row >> 5, h = row & 31;
        const int fl = *flagws;

        #pragma unroll
        for (int r = 0; r < 3; ++r) {
            const int hh = h + r - 1;
            if (t < 64) {
                const int s = (t >> 5) ? 33 : 0, cq = t & 31;
                *(uint4*)(xs + (r * 34 + s) * 264 + cq * 8) = make_uint4(0, 0, 0, 0);
            }
            const bool ok = (hh >= 0) && (hh < 32);
            const u16* src = xbf + ((size_t)((b * 32 + (ok ? hh : 0)) * 32)) * 256;
            #pragma unroll
            for (int i = 0; i < 4; ++i) {
                const int idx = t + i * 256;
                const int px = idx >> 5, cq = idx & 31;
                uint4 v = ok ? *(const uint4*)(src + px * 256 + cq * 8)
                             : make_uint4(0, 0, 0, 0);
                *(uint4*)(xs + (r * 34 + 1 + px) * 264 + cq * 8) = v;
            }
        }
        __syncthreads();

        const int tg0 = coh * 6 + (wave >> 1) * 3;
        f32x4 acc[3] = {{0,0,0,0},{0,0,0,0},{0,0,0,0}};

        #pragma unroll
        for (int p = 0; p < 9; ++p) {
            const int kh = p / 3, kw = p - kh * 3;
            const u16* ap = xs + (kh * 34 + kw + Mtile * 16 + l15) * 264 + quad * 8;
            #pragma unroll
            for (int ck = 0; ck < 8; ++ck) {
                const int kk = p * 8 + ck;
                const bf16x8 av = *(const bf16x8*)(ap + ck * 32);
                const u16* wp = wshC + ((size_t)(kk * 12 + tg0) * 64 + lane) * 8;
                const bf16x8 b0 = *(const bf16x8*)(wp);
                const bf16x8 b1 = *(const bf16x8*)(wp + 512);
                const bf16x8 b2 = *(const bf16x8*)(wp + 1024);
                acc[0] = __builtin_amdgcn_mfma_f32_16x16x32_bf16(av, b0, acc[0], 0, 0, 0);
                acc[1] = __builtin_amdgcn_mfma_f32_16x16x32_bf16(av, b1, acc[1], 0, 0, 0);
                acc[2] = __builtin_amdgcn_mfma_f32_16x16x32_bf16(av, b2, acc[2], 0, 0, 0);
            }
        }

        const int px0 = Mtile * 16 + quad * 4;
        #pragma unroll
        for (int ti = 0; ti < 3; ++ti) {
            const int co = (tg0 + ti) * 16 + l15;
            const float bias = cbf[co];
            #pragma unroll
            for (int r = 0; r < 4; ++r) {
                const size_t oidx = ((size_t)row * 32 + px0 + r) * 256 + co;
                const float v = acc[ti][r] + bias;
                if (fl) ((u16*)out)[oidx] = f2bf(v);
                else    ((float*)out)[oidx] = v;
            }
        }
    } else {
        // ================= qkv role (verified body) =================
        const int idx2 = blk - 512;
        const int coh = idx2 & 1, row = idx2 >> 1;
        const int b = row >> 5, h = row & 31;

        {
            const u16* src = xbf + (size_t)row * 8192;
            #pragma unroll
            for (int i = 0; i < 4; ++i) {
                const int idx = t + i * 256;
                const int px = idx >> 5, cq = idx & 31;
                *(uint4*)(xs + px * 264 + cq * 8) = *(const uint4*)(src + px * 256 + cq * 8);
            }
        }
        __syncthreads();

        const int tg0 = coh * 6 + (wave >> 1) * 3;
        f32x4 acc[3] = {{0,0,0,0},{0,0,0,0},{0,0,0,0}};

        const u16* ap = xs + (Mtile * 16 + l15) * 264 + quad * 8;
        #pragma unroll
        for (int kk = 0; kk < 8; ++kk) {
            const bf16x8 av = *(const bf16x8*)(ap + kk * 32);
            const u16* wp = wshQ + ((size_t)(kk * 12 + tg0) * 64 + lane) * 8;
            const bf16x8 b0 = *(const bf16x8*)(wp);
            const bf16x8 b1 = *(const bf16x8*)(wp + 512);
            const bf16x8 b2 = *(const bf16x8*)(wp + 1024);
            acc[0] = __builtin_amdgcn_mfma_f32_16x16x32_bf16(av, b0, acc[0], 0, 0, 0);
            acc[1] = __builtin_amdgcn_mfma_f32_16x16x32_bf16(av, b1, acc[1], 0, 0, 0);
            acc[2] = __builtin_amdgcn_mfma_f32_16x16x32_bf16(av, b2, acc[2], 0, 0, 0);
        }

        // D layout (verified): col = lane&15, row = quad*4 + reg
        const int px0 = Mtile * 16 + quad * 4;
        #pragma unroll
        for (int ti = 0; ti < 3; ++ti) {
            const int tg = tg0 + ti;
            const int o = tg * 16 + l15;
            const int third = tg >> 2;                      // 0=k,1=q,2=v (wave-uniform)
            const int within = o - third * 64;
            const int n = within >> 3, d = within & 7;
            const float bias = qbf_[o];
            #pragma unroll
            for (int r = 0; r < 4; ++r) {
                const int i = h * 32 + px0 + r;
                const size_t off = ((size_t)(b * 8 + n) * 1024 + i) * 8 + d;
                const float val = acc[ti][r] + bias;
                if (third == 0)      kb16[off] = f2bf(val);
                else if (third == 1) qbuf[off] = val * 0.51006973050f;  // 8^-.5 * log2e
                else                 vb16[off] = f2bf(val);
            }
        }
    }
}

// ---------------------------------------------------------------------------
// MFMA flash attention v10 — GREEN (R9-verified). Unchanged.
// ---------------------------------------------------------------------------
#define ATTN_STEPA(C, KA, KB, OACC)                                            \
  do {                                                                         \
    const int c_ = (C);                                                        \
    const float rhv = sRH[c_ * 36 + pair * 16 + l15];                          \
    f32x4 acc0, acc1;                                                          \
    acc0[0] = rhv + rw0[0]; acc0[1] = rhv + rw0[1];                            \
    acc0[2] = rhv + rw0[2]; acc0[3] = rhv + rw0[3];                            \
    acc1[0] = rhv + rw1[0]; acc1[1] = rhv + rw1[1];                            \
    acc1[2] = rhv + rw1[2]; acc1[3] = rhv + rw1[3];                            \
    acc0 = __builtin_amdgcn_mfma_f32_16x16x32_bf16(KA, Aq.v, acc0, 0, 0, 0);   \
    acc1 = __builtin_amdgcn_mfma_f32_16x16x32_bf16(KB, Aq.v, acc1, 0, 0, 0);   \
    if (c_ + 4 < 32) {            /* prefetch 4 chunks ahead (ping-pong) */    \
      KA = *(const bf16x8*)(kp0 + (c_ + 4) * 256);                             \
      KB = *(const bf16x8*)(kp1 + (c_ + 4) * 256);                             \
    }                                                                          \
    union { u16 a[8]; bf16x8 v; } pf;                                          \
    pf.a[0] = bf16u(fexp2(fminf(acc0[0], 80.0f)));                             \
    pf.a[1] = bf16u(fexp2(fminf(acc0[1], 80.0f)));                             \
    pf.a[2] = bf16u(fexp2(fminf(acc0[2], 80.0f)));                             \
    pf.a[3] = bf16u(fexp2(fminf(acc0[3], 80.0f)));                             \
    pf.a[4] = bf16u(fexp2(fminf(acc1[0], 80.0f)));                             \
    pf.a[5] = bf16u(fexp2(fminf(acc1[1], 80.0f)));                             \
    pf.a[6] = bf16u(fexp2(fminf(acc1[2], 80.0f)));                             \
    pf.a[7] = bf16u(fexp2(fminf(acc1[3], 80.0f)));                             \
    bf16x8 Av;                                                                 \
    if (l15 < 8) Av = *(const bf16x8*)(sVT + l15 * 1032 + c_ * 32 + quad * 8); \
    else         Av = ONE.v;                                                   \
    OACC = __builtin_amdgcn_mfma_f32_16x16x32_bf16(Av, pf.v, OACC, 0, 0, 0);   \
  } while (0)

__global__ __launch_bounds__(256) void attn_mfma_kernel(
    const u16* __restrict__ kb16, const float* __restrict__ qbuf, const u16* __restrict__ vb16,
    const float* __restrict__ krw, const float* __restrict__ krh,
    float* __restrict__ attnbuf)
{
    const int qb = blockIdx.x;           // 0..31 (32 q-rows each)
    const int bn = blockIdx.y;           // 0..63
    const int b = bn >> 3, hn = bn & 7;
    const int t = threadIdx.x;
    const int i0 = qb * 32;

    __shared__ __align__(16) u16   sVT[8 * 1032];   // [d][key] bf16 (pad)  16512 B
    __shared__ __align__(16) u16   sRW[32 * 40];    // [ilocal][wk] bf16     2560 B
    __shared__ __align__(16) float sRH[32 * 36];    // [hk][ilocal] f32      4608 B
    __shared__ __align__(16) float sRed[2 * 64 * 4];// pair partials         2048 B

    // ---- stage V^T from bf16 vbuf (no conversion) — verified ----
    const u16* vg = vb16 + (size_t)bn * 8192;
    #pragma unroll
    for (int k4 = 0; k4 < 4; k4++) {
        const int key = t + k4 * 256;                 // 0..1023
        uint4 vv = *(const uint4*)(vg + key * 8);
        sVT[0 * 1032 + key] = (u16)(vv.x);  sVT[1 * 1032 + key] = (u16)(vv.x >> 16);
        sVT[2 * 1032 + key] = (u16)(vv.y);  sVT[3 * 1032 + key] = (u16)(vv.y >> 16);
        sVT[4 * 1032 + key] = (u16)(vv.z);  sVT[5 * 1032 + key] = (u16)(vv.z >> 16);
        sVT[6 * 1032 + key] = (u16)(vv.w);  sVT[7 * 1032 + key] = (u16)(vv.w >> 16);
    }
    // ---- rel tables (verified math; 32 q-rows) ----
    #pragma unroll
    for (int k8 = 0; k8 < 4; k8++) {
        const int idx = t + k8 * 256;                 // 0..1023
        const int il = idx >> 5, w = idx & 31;        // il 0..31
        const int i = i0 + il;
        const float* q = qbuf + ((size_t)bn * 1024 + i) * 8;
        float4 qa = *(const float4*)q, qc = *(const float4*)(q + 4);
        const float* rp = krw + (size_t)(w - (i & 31) + 31) * 8;
        float4 ra = *(const float4*)rp, rc = *(const float4*)(rp + 4);
        sRW[il * 40 + w] = f2bf(qa.x*ra.x + qa.y*ra.y + qa.z*ra.z + qa.w*ra.w
                              + qc.x*rc.x + qc.y*rc.y + qc.z*rc.z + qc.w*rc.w);
        const float* hp = krh + (size_t)(w - (i >> 5) + 31) * 8;
        float4 ha = *(const float4*)hp, hc = *(const float4*)(hp + 4);
        sRH[w * 36 + il] = qa.x*ha.x + qa.y*ha.y + qa.z*ha.z + qa.w*ha.w
                         + qc.x*hc.x + qc.y*hc.y + qc.z*hc.z + qc.w*hc.w;
    }
    __syncthreads();

    const int lane = t & 63, wave = t >> 6;
    const int pair = wave >> 1, sub = wave & 1;
    const int l15 = lane & 15, quad = lane >> 4;

    union Frag { u16 a[8]; bf16x8 v; };
    Frag Aq;                                   // Q fragment (B operand)
    {
        const float* q = qbuf + ((size_t)bn * 1024 + i0 + pair * 16 + l15) * 8;
        float4 qa = *(const float4*)q, qc = *(const float4*)(q + 4);
        Aq.a[0] = f2bf(qa.x); Aq.a[1] = f2bf(qa.y); Aq.a[2] = f2bf(qa.z); Aq.a[3] = f2bf(qa.w);
        Aq.a[4] = f2bf(qc.x); Aq.a[5] = f2bf(qc.y); Aq.a[6] = f2bf(qc.z); Aq.a[7] = f2bf(qc.w);
        if (quad != 0) {
            #pragma unroll
            for (int j = 0; j < 8; j++) Aq.a[j] = 0;
        }
    }
    const bf16x8 Arw = *(const bf16x8*)(sRW + (pair * 16 + l15) * 40 + quad * 8);

    // Selector fragments (verified): S0 -> k=pi0(l15), S1 -> k=pi1(l15).
    Frag S0, S1, ONE;
    #pragma unroll
    for (int j = 0; j < 8; j++) { S0.a[j] = 0; S1.a[j] = 0; ONE.a[j] = 0x3F80; }
    if (quad == (l15 >> 2)) {
        S0.a[l15 & 3]       = 0x3F80;
        S1.a[4 + (l15 & 3)] = 0x3F80;
    }

    // Hoisted rel-W results (chunk-invariant).
    f32x4 zero4 = {0.f, 0.f, 0.f, 0.f};
    const f32x4 rw0 = __builtin_amdgcn_mfma_f32_16x16x32_bf16(S0.v, Arw, zero4, 0, 0, 0);
    const f32x4 rw1 = __builtin_amdgcn_mfma_f32_16x16x32_bf16(S1.v, Arw, zero4, 0, 0, 0);

    // K row pointers — uniform across quads (verified).
    const u16* kg = kb16 + (size_t)bn * 8192;
    const int s = l15 >> 2, rr = l15 & 3;
    const u16* kp0 = kg + (size_t)(8 * s + rr) * 8;          // pi0 rows
    const u16* kp1 = kg + (size_t)(8 * s + 4 + rr) * 8;      // pi1 rows

    f32x4 oaccE = {0.f, 0.f, 0.f, 0.f};
    f32x4 oaccO = {0.f, 0.f, 0.f, 0.f};

    // This wave's chunks: sub, sub+2, ..., sub+30 (16 chunks).
    bf16x8 kAa = *(const bf16x8*)(kp0 + sub * 256);
    bf16x8 kBa = *(const bf16x8*)(kp1 + sub * 256);
    bf16x8 kAb = *(const bf16x8*)(kp0 + (sub + 2) * 256);
    bf16x8 kBb = *(const bf16x8*)(kp1 + (sub + 2) * 256);

    for (int c2 = sub; c2 < 32; c2 += 4) {
        ATTN_STEPA(c2,     kAa, kBa, oaccE);
        ATTN_STEPA(c2 + 2, kAb, kBb, oaccO);
    }

    f32x4 oacc;
    oacc[0] = oaccE[0] + oaccO[0];
    oacc[1] = oaccE[1] + oaccO[1];
    oacc[2] = oaccE[2] + oaccO[2];
    oacc[3] = oaccE[3] + oaccO[3];

    // Pair reduction: sub==1 writes partials; sub==0 adds.
    if (sub == 1) *(f32x4*)(sRed + (pair * 64 + lane) * 4) = oacc;
    __syncthreads();
    if (sub == 0) {
        const f32x4 part = *(const f32x4*)(sRed + (pair * 64 + lane) * 4);
        oacc[0] += part[0]; oacc[1] += part[1];
        oacc[2] += part[2]; oacc[3] += part[3];

        // D2[row][q=l15]: rows 0-7 = O^T[d][q] (quads 0,1), rows 8-15 = l[q].
        const float lr = __shfl(oacc[0], 32 + l15, 64);   // (l15, quad=2) row 8
        const float inv = 1.0f / fmaxf(lr, 1e-30f);
        if (quad < 2) {
            float4 o;
            o.x = oacc[0] * inv; o.y = oacc[1] * inv;
            o.z = oacc[2] * inv; o.w = oacc[3] * inv;
            *(float4*)(attnbuf + ((size_t)b * 1024 + i0 + pair * 16 + l15) * 64
                       + hn * 8 + quad * 4) = o;
        }
    }
}

// ---------------------------------------------------------------------------
// Output projection (verified body; flag read from ws).
// ---------------------------------------------------------------------------
__global__ __launch_bounds__(256) void proj_kernel(
    const float* __restrict__ attnbuf, const float* __restrict__ awf, const float* __restrict__ abf,
    const int* __restrict__ flagws, void* __restrict__ out)
{
    const int g = blockIdx.x * 256 + threadIdx.x;
    const int px = g >> 6, o = g & 63;
    const float* ar = attnbuf + (size_t)px * 64;
    float acc = abf[o];
    #pragma unroll 8
    for (int c = 0; c < 64; c++) acc += ar[c] * awf[c * 64 + o];
    if (*flagws) ((u16*)out)[(size_t)px * 256 + 192 + o] = f2bf(acc);
    else         ((float*)out)[(size_t)px * 256 + 192 + o] = acc;
}

// ---------------------------------------------------------------------------
extern "C" void kernel_launch(void* const* d_in, const int* in_sizes, int n_in,
                              void* d_out, int out_size, void* d_ws, size_t ws_size,
                              hipStream_t stream)
{
    float* ws = (float*)d_ws;
    int*   flag = (int*)(ws + FLAG_OFF);
    float* zbuf = ws + ZERO_OFF;
    u16*   wsh  = (u16*)(ws + WSH_OFF);
    float* awf  = ws + AWF_OFF;
    float* cbf  = ws + CBF_OFF;
    float* qbf  = ws + QBF_OFF;
    float* abf  = ws + ABF_OFF;
    float* krw  = ws + KRW_OFF;
    float* krh  = ws + KRH_OFF;
    u16*   kb16 = (u16*)(ws + KB_OFF);
    float* qbuf = ws + QB_OFF;
    u16*   vb16 = (u16*)(ws + VB_OFF);
    float* atb  = ws + AT_OFF;
    u16*   xbf  = (u16*)(ws + XBF_OFF);
    u16*   wshQ = (u16*)(ws + WSHQ_OFF);

    prepx_kernel<<<1286, 256, 0, stream>>>(
        (const u16*)d_in[0],
        d_in[1], d_in[3], d_in[2], d_in[4], d_in[5], d_in[6], d_in[7], d_in[8],
        wsh, wshQ, cbf, qbf, awf, abf, krw, krh, zbuf, flag, xbf);

    qc_kernel<<<1024, 256, 0, stream>>>(
        xbf, wsh, wshQ, cbf, qbf, flag, kb16, qbuf, vb16, d_out);

    attn_mfma_kernel<<<dim3(32, 64), 256, 0, stream>>>(kb16, qbuf, vb16, krw, krh, atb);
    proj_kernel     <<<2048,         256, 0, stream>>>(atb, awf, abf, flag, d_out);
}